// Round 3
// baseline (902.311 us; speedup 1.0000x reference)
//
#include <hip/hip_runtime.h>
#include <hip/hip_bf16.h>
#include <hip/hip_cooperative_groups.h>

namespace cg = cooperative_groups;

// ---------------------------------------------------------------------------
// PointNet++ critic forward. B=32, N=4096.
// R19 = R13 kernels (fps scalar latency-floor form; R18's 64-block fused3
// REVERTED: -parallelism fusion cost +50us) + dispatch-count reduction that
// PRESERVES per-block structure:
//   * bq2 inlined into mlp2 (wave-0 ball query from LDS copy, identical
//     arithmetic/order; removes dispatch + gidx2 round-trip)
//   * g1+g2+g3+fchead as ONE cooperative kernel, 256 blocks (1/CU),
//     grid.sync() between layers; per-block instruction streams identical
//     to the old gemm_mfma launches (L2: 2 bo's/block, L3: 4 bo's/block).
// 9 -> 5 dispatches. Theory: ~200-250us of the 450us non-fps budget is
// launch/drain overhead, not kernel work.
// ---------------------------------------------------------------------------

typedef __attribute__((ext_vector_type(8))) short short8;
typedef __attribute__((ext_vector_type(4))) float f32x4;
union SV8 { short8 v; ushort u[8]; };

__device__ __forceinline__ ushort f2bf(float x) {
    unsigned u = __float_as_uint(x);
    unsigned r = (u + 0x7fffu + ((u >> 16) & 1u)) >> 16;   // RNE
    return (ushort)r;
}

// ======================= DPP wave64 max-reduce (u64) =======================
template<int CTRL>
__device__ __forceinline__ unsigned long long dpp_mov_u64(unsigned long long x) {
    const int lo = (int)(unsigned)(x & 0xffffffffull);
    const int hi = (int)(unsigned)(x >> 32);
    const int nlo = __builtin_amdgcn_update_dpp(lo, lo, CTRL, 0xf, 0xf, false);
    const int nhi = __builtin_amdgcn_update_dpp(hi, hi, CTRL, 0xf, 0xf, false);
    return ((unsigned long long)(unsigned)nhi << 32) | (unsigned)nlo;
}

__device__ __forceinline__ unsigned long long wave_max_u64(unsigned long long x) {
    unsigned long long y;
    y = dpp_mov_u64<0x111>(x); if (y > x) x = y;   // row_shr:1
    y = dpp_mov_u64<0x112>(x); if (y > x) x = y;   // row_shr:2
    y = dpp_mov_u64<0x114>(x); if (y > x) x = y;   // row_shr:4
    y = dpp_mov_u64<0x118>(x); if (y > x) x = y;   // row_shr:8
    y = dpp_mov_u64<0x142>(x); if (y > x) x = y;   // row_bcast:15
    y = dpp_mov_u64<0x143>(x); if (y > x) x = y;   // row_bcast:31
    return x;
}

// ============================ FPS body (R12/R13) ===========================
template<int N, int S, int NT, bool CHW>
__device__ __forceinline__ void fps_body(const float* __restrict__ xyz,
                                         float* __restrict__ new_xyz,
                                         int b, int t, char* smem) {
    constexpr int P  = N / NT;
    constexpr int NW = NT / 64;
    float4* sxyz = (float4*)smem;
    unsigned long long* rv = (unsigned long long*)(smem + (size_t)N * 16);
    int* sfar = (int*)(smem + (size_t)N * 16 + 2 * NW * 8);
    float px[P], py[P], pz[P], dist[P];
    unsigned idc[P];
    if (CHW) {
        const float* base = xyz + (size_t)b * 3 * N;
        #pragma unroll
        for (int p = 0; p < P; ++p) {
            const int i = p * NT + t;
            px[p] = base[i]; py[p] = base[N + i]; pz[p] = base[2 * N + i];
            sxyz[i] = make_float4(px[p], py[p], pz[p], 0.0f);
        }
    } else {
        const float* base = xyz + (size_t)b * N * 3;
        #pragma unroll
        for (int p = 0; p < P; ++p) {
            const int i = p * NT + t;
            px[p] = base[i*3]; py[p] = base[i*3+1]; pz[p] = base[i*3+2];
            sxyz[i] = make_float4(px[p], py[p], pz[p], 0.0f);
        }
    }
    #pragma unroll
    for (int p = 0; p < P; ++p) { dist[p] = 1e10f; idc[p] = (unsigned)(N - 1 - (p * NT + t)); }
    __syncthreads();
    int far = 0;
    for (int j = 0; j < S; ++j) {
        if (t == 0) sfar[j] = far;           // LDS only — no VMEM in loop
        const float4 cen = sxyz[far];        // broadcast b128
        unsigned long long pk[P];
        #pragma unroll
        for (int p = 0; p < P; ++p) {
            const float dx = px[p] - cen.x, dy = py[p] - cen.y, dz = pz[p] - cen.z;
            // match reference rounding exactly: no FMA contraction
            const float d = __fadd_rn(__fadd_rn(__fmul_rn(dx, dx), __fmul_rn(dy, dy)), __fmul_rn(dz, dz));
            const float nd = fminf(dist[p], d);
            dist[p] = nd;
            pk[p] = ((unsigned long long)__float_as_uint(nd) << 32) | idc[p];
        }
        #pragma unroll
        for (int s = P / 2; s > 0; s >>= 1)
            #pragma unroll
            for (int k = 0; k < s; ++k)
                if (pk[k + s] > pk[k]) pk[k] = pk[k + s];
        unsigned long long best = wave_max_u64(pk[0]);
        if constexpr (NW > 1) {
            const int sl = (j & 1) * NW;     // parity slots: overwrite-safe
            if ((t & 63) == 63) rv[sl + (t >> 6)] = best;
            __syncthreads();
            unsigned long long bb = rv[sl];
            #pragma unroll
            for (int w = 1; w < NW; ++w) { const unsigned long long v = rv[sl + w]; if (v > bb) bb = v; }
            far = N - 1 - (int)(bb & 0xffffffffull);
        } else {
            far = N - 1 - __builtin_amdgcn_readlane((int)(best & 0xffffffffull), 63);
        }
    }
    __syncthreads();
    float* out = new_xyz + (size_t)b * S * 3;
    for (int i = t; i < S; i += NT) {
        const float4 c = sxyz[sfar[i]];
        out[i*3+0] = c.x; out[i*3+1] = c.y; out[i*3+2] = c.z;
    }
}

// ==================== weight bf16 tile pack (h only) =======================
__device__ __forceinline__ void packg(const float* __restrict__ src,
                                      ushort* __restrict__ dh,
                                      int Ktot, int otiles, int cofs, int idx) {
    const int j = idx & 7, lane = (idx >> 3) & 63;
    const int ot = (idx >> 9) % otiles;
    const int ks = idx / (512 * otiles);
    const int m = lane & 15, q = lane >> 4;
    const int o = ot * 16 + m, c = cofs + ks * 32 + q * 8 + j;
    const float v = (c < Ktot) ? src[(size_t)o * Ktot + c] : 0.0f;
    dh[idx] = f2bf(v);
}

// ================= fps1 + weight pack, merged launch =======================
__global__ __launch_bounds__(256)
void fps1_prep_kernel(const float* __restrict__ xyz, float* __restrict__ l1xyz,
                 const float* s1w0, const float* s1b0, float4* Wc1,
                 const float* s1w1, ushort* M1W1h,
                 const float* s1w2, ushort* M1W2h,
                 const float* s3w0, ushort* S3W0h,
                 const float* s3w1, ushort* S3W1h,
                 const float* s3w2, ushort* S3W2h,
                 const float* s2w0, const float* s2b0, float4* Wc0,
                 ushort* W0h,
                 const float* s2w1, ushort* W1h,
                 const float* s2w2, ushort* W2h) {
    __shared__ __align__(16) char smem[4096 * 16 + 64 + 512 * 4];
    if (blockIdx.x < 32) {
        fps_body<4096, 512, 256, true>(xyz, l1xyz, blockIdx.x, threadIdx.x, smem);
        return;
    }
    int i = (blockIdx.x - 32) * 256 + threadIdx.x;
    if (i < 64)     { Wc1[i] = make_float4(s1w0[i*3], s1w0[i*3+1], s1w0[i*3+2], s1b0[i]); return; }  i -= 64;
    if (i < 4096)   { packg(s1w1, M1W1h,  64,  4, 0, i); return; }   i -= 4096;
    if (i < 8192)   { packg(s1w2, M1W2h,  64,  8, 0, i); return; }   i -= 8192;
    if (i < 73728)  { packg(s3w0, S3W0h, 259, 16, 0, i); return; }   i -= 73728;
    if (i < 131072) { packg(s3w1, S3W1h, 256, 32, 0, i); return; }   i -= 131072;
    if (i < 524288) { packg(s3w2, S3W2h, 512, 64, 0, i); return; }   i -= 524288;
    if (i < 16384)  { packg(s2w0, W0h, 131,  8, 3, i); return; }     i -= 16384;
    if (i < 16384)  { packg(s2w1, W1h, 128,  8, 0, i); return; }     i -= 16384;
    if (i < 32768)  { packg(s2w2, W2h, 128, 16, 0, i); return; }     i -= 32768;
    if (i < 128) {
        Wc0[i] = make_float4(s2w0[(size_t)i*131+0], s2w0[(size_t)i*131+1],
                             s2w0[(size_t)i*131+2], s2b0[i]);
    }
}

// ============================ Ball query (stage 1) =========================
template<int N, int NS, bool CHW, int NT>
__global__ __launch_bounds__(NT)
void bq_kernel(float r2, const float* __restrict__ xyz, const float* __restrict__ cen,
               int* __restrict__ gidx, int S) {
    constexpr int WPB = NT / 64;
    __shared__ __align__(16) float4 sp[N];
    const int t = threadIdx.x, lane = t & 63, w = t >> 6;
    const int cen0 = blockIdx.x * WPB;
    const int b = cen0 / S;                     // WPB divides S -> same batch
    if (CHW) {
        const float* base = xyz + (size_t)b * 3 * N;
        for (int i = t; i < N; i += NT)
            sp[i] = make_float4(base[i], base[N + i], base[2 * N + i], 0.0f);
    } else {
        const float* base = xyz + (size_t)b * N * 3;
        for (int i = t; i < N; i += NT)
            sp[i] = make_float4(base[i*3], base[i*3+1], base[i*3+2], 0.0f);
    }
    __syncthreads();
    const int wid = cen0 + w;
    const float cx = cen[(size_t)wid*3+0], cy = cen[(size_t)wid*3+1], cz = cen[(size_t)wid*3+2];
    int* out = gidx + (size_t)wid * NS;
    int cnt = 0, first = -1;
    for (int b0 = 0; b0 < N; b0 += 64) {
        const float4 p = sp[b0 + lane];
        const float dx = p.x - cx, dy = p.y - cy, dz = p.z - cz;
        const float d = __fadd_rn(__fadd_rn(__fmul_rn(dx, dx), __fmul_rn(dy, dy)), __fmul_rn(dz, dz));
        const bool in = (d <= r2);
        const unsigned long long m = __ballot(in);
        if (first < 0 && m != 0ull) first = b0 + __ffsll((unsigned long long)m) - 1;
        const int pos = cnt + (int)__popcll(m & ((1ull << lane) - 1ull));
        if (in && pos < NS) out[pos] = b0 + lane;
        cnt += (int)__popcll(m);
        if (cnt >= NS) break;
    }
    if (cnt < NS)
        for (int k = cnt + lane; k < NS; k += 64) out[k] = first;
}

// ==================== MLP stage 1 (MFMA bf16) + fps2 merged ================
__global__ __launch_bounds__(256)
void mlp1_kernel(const float* __restrict__ xyz, const float* __restrict__ l1xyz,
                 float* __restrict__ l2xyz,
                 const int* __restrict__ gidx, const float4* __restrict__ Wc1,
                 const ushort* __restrict__ W1h, const float* __restrict__ b1,
                 const ushort* __restrict__ W2h, const float* __restrict__ b2,
                 float* __restrict__ l1p) {
    __shared__ __align__(16) char smem[64 * 68 * 4 * 2];   // 34816 B
    float* bufA = (float*)smem;
    float* bufB = (float*)(smem + 64 * 68 * 4);
    const int t = threadIdx.x, b = blockIdx.y;
    if (blockIdx.x == 256) {   // fps2
        fps_body<512, 128, 256, false>(l1xyz, l2xyz, b, t, smem);
        return;
    }
    const int s0 = blockIdx.x * 2;
    {
        const int n = t >> 2, c = t & 3;
        const int s = s0 + (n >> 5);
        const int gi = gidx[((size_t)b * 512 + s) * 32 + (n & 31)];
        float v = 0.0f;
        if (c < 3) v = xyz[(size_t)b * 3 * 4096 + c * 4096 + gi] - l1xyz[((size_t)b * 512 + s) * 3 + c];
        bufB[n * 4 + c] = v;
    }
    __syncthreads();
    {   // layer0: 3 -> 64, exact fp32
        const int o = t & 63, ng = t >> 6;
        const float4 wc = Wc1[o];
        #pragma unroll
        for (int r = 0; r < 16; ++r) {
            const int n = ng * 16 + r;
            const float z = wc.w + wc.x * bufB[n*4] + wc.y * bufB[n*4+1] + wc.z * bufB[n*4+2];
            bufA[n * 68 + o] = fmaxf(z, 0.0f);
        }
    }
    const int lane = t & 63, wv = t >> 6;
    const int m = lane & 15, q = lane >> 4;
    const int rowA = wv * 16 + m;
    // layer1: 64 -> 64
    f32x4 acc1[4];
    #pragma unroll
    for (int ot = 0; ot < 4; ++ot)
        #pragma unroll
        for (int r = 0; r < 4; ++r) acc1[ot][r] = 0.0f;
    #pragma unroll
    for (int ks = 0; ks < 2; ++ks) {
        float xv[8];
        *(float4*)&xv[0] = *(const float4*)&bufA[rowA * 68 + ks * 32 + q * 8];
        *(float4*)&xv[4] = *(const float4*)&bufA[rowA * 68 + ks * 32 + q * 8 + 4];
        SV8 ah;
        #pragma unroll
        for (int j = 0; j < 8; ++j) ah.u[j] = f2bf(xv[j]);
        #pragma unroll
        for (int ot = 0; ot < 4; ++ot) {
            SV8 bh;
            bh.v = *(const short8*)(W1h + (size_t)((ks * 4 + ot) * 64 + lane) * 8);
            acc1[ot] = __builtin_amdgcn_mfma_f32_16x16x32_bf16(ah.v, bh.v, acc1[ot], 0, 0, 0);
        }
    }
    #pragma unroll
    for (int ot = 0; ot < 4; ++ot) {
        const float bb = b1[ot * 16 + m];
        #pragma unroll
        for (int r = 0; r < 4; ++r)
            bufB[(wv * 16 + q * 4 + r) * 68 + ot * 16 + m] = fmaxf(acc1[ot][r] + bb, 0.0f);
    }
    // layer2: 64 -> 128 + per-wave max
    f32x4 acc2[8];
    #pragma unroll
    for (int ot = 0; ot < 8; ++ot)
        #pragma unroll
        for (int r = 0; r < 4; ++r) acc2[ot][r] = 0.0f;
    #pragma unroll
    for (int ks = 0; ks < 2; ++ks) {
        float xv[8];
        *(float4*)&xv[0] = *(const float4*)&bufB[rowA * 68 + ks * 32 + q * 8];
        *(float4*)&xv[4] = *(const float4*)&bufB[rowA * 68 + ks * 32 + q * 8 + 4];
        SV8 ah;
        #pragma unroll
        for (int j = 0; j < 8; ++j) ah.u[j] = f2bf(xv[j]);
        #pragma unroll
        for (int ot = 0; ot < 8; ++ot) {
            SV8 bh;
            bh.v = *(const short8*)(W2h + (size_t)((ks * 8 + ot) * 64 + lane) * 8);
            acc2[ot] = __builtin_amdgcn_mfma_f32_16x16x32_bf16(ah.v, bh.v, acc2[ot], 0, 0, 0);
        }
    }
    __syncthreads();
    #pragma unroll
    for (int ot = 0; ot < 8; ++ot) {
        const float bb = b2[ot * 16 + m];
        float mx = 0.0f;
        #pragma unroll
        for (int r = 0; r < 4; ++r) mx = fmaxf(mx, acc2[ot][r] + bb);
        bufA[(wv * 4 + q) * 128 + ot * 16 + m] = mx;
    }
    __syncthreads();
    {
        const int half = t >> 7, o = t & 127;
        float v = bufA[(half * 8) * 128 + o];
        #pragma unroll
        for (int rr = 1; rr < 8; ++rr) v = fmaxf(v, bufA[(half * 8 + rr) * 128 + o]);
        l1p[((size_t)b * 512 + s0 + half) * 128 + o] = v;
    }
}

// ============== MLP stage 2 (MFMA bf16) with INLINE ball query =============
__global__ __launch_bounds__(256)
void mlp2_kernel(const float* __restrict__ l1xyz, const float* __restrict__ l1p,
                 const float* __restrict__ l2xyz,
                 const ushort* __restrict__ W0h, const float4* __restrict__ Wc0,
                 const ushort* __restrict__ W1h, const float* __restrict__ b1,
                 const ushort* __restrict__ W2h, const float* __restrict__ b2,
                 float* __restrict__ X3) {
    __shared__ __align__(16) float Abuf[64 * 132];   // x / h2
    __shared__ __align__(16) float Bbuf[64 * 132];   // h1 / max-partials
    __shared__ int sg[64];
    __shared__ __align__(16) float4 sp4[512];        // batch's 512 l1 points
    const int t = threadIdx.x, bs = blockIdx.x, b = bs >> 7;
    {   // stage the batch's 512 points (row-major l1xyz)
        const float* base = l1xyz + (size_t)b * 512 * 3;
        for (int i = t; i < 512; i += 256)
            sp4[i] = make_float4(base[i*3], base[i*3+1], base[i*3+2], 0.0f);
    }
    if (t < 3)  X3[(size_t)bs * 288 + t] = l2xyz[(size_t)bs * 3 + t];     // raw coords
    if (t >= 64 && t < 93) X3[(size_t)bs * 288 + 259 + (t - 64)] = 0.0f;  // zero pad
    __syncthreads();
    if (t < 64) {   // inline ball query for this centroid (wave 0) -> sg
        const float r2 = (float)(0.4 * 0.4);
        const float cx = l2xyz[(size_t)bs*3+0], cy = l2xyz[(size_t)bs*3+1], cz = l2xyz[(size_t)bs*3+2];
        int cnt = 0, first = -1;
        for (int b0 = 0; b0 < 512; b0 += 64) {
            const float4 p = sp4[b0 + t];
            const float dx = p.x - cx, dy = p.y - cy, dz = p.z - cz;
            const float d = __fadd_rn(__fadd_rn(__fmul_rn(dx, dx), __fmul_rn(dy, dy)), __fmul_rn(dz, dz));
            const bool in = (d <= r2);
            const unsigned long long mm = __ballot(in);
            if (first < 0 && mm != 0ull) first = b0 + __ffsll((unsigned long long)mm) - 1;
            const int pos = cnt + (int)__popcll(mm & ((1ull << t) - 1ull));
            if (in && pos < 64) sg[pos] = b0 + t;
            cnt += (int)__popcll(mm);
            if (cnt >= 64) break;
        }
        if (cnt < 64)
            for (int k = cnt + t; k < 64; k += 64) sg[k] = first;
    }
    __syncthreads();
    for (int i = t; i < 64 * 32; i += 256) {
        const int n = i >> 5, cc = i & 31;
        *(float4*)&Abuf[n * 132 + cc * 4] =
            *(const float4*)&l1p[((size_t)b * 512 + sg[n]) * 128 + cc * 4];
    }
    if (t < 192) {
        const int n = t / 3, c = t % 3;
        const float4 pp = sp4[sg[n]];
        const float pc = (c == 0) ? pp.x : (c == 1) ? pp.y : pp.z;
        Abuf[n * 132 + 128 + c] = pc - l2xyz[(size_t)bs * 3 + c];
    }
    __syncthreads();
    const int lane = t & 63, wv = t >> 6;
    const int m = lane & 15, q = lane >> 4;
    const int rowA = wv * 16 + m;

    // layer 0: feats (K=128) MFMA + coords/bias epilogue
    f32x4 acc0[8];
    #pragma unroll
    for (int ot = 0; ot < 8; ++ot)
        #pragma unroll
        for (int r = 0; r < 4; ++r) acc0[ot][r] = 0.0f;
    #pragma unroll
    for (int ks = 0; ks < 4; ++ks) {
        float xv[8];
        *(float4*)&xv[0] = *(const float4*)&Abuf[rowA * 132 + ks * 32 + q * 8];
        *(float4*)&xv[4] = *(const float4*)&Abuf[rowA * 132 + ks * 32 + q * 8 + 4];
        SV8 ah;
        #pragma unroll
        for (int j = 0; j < 8; ++j) ah.u[j] = f2bf(xv[j]);
        #pragma unroll
        for (int ot = 0; ot < 8; ++ot) {
            SV8 bh;
            bh.v = *(const short8*)(W0h + (size_t)((ks * 8 + ot) * 64 + lane) * 8);
            acc0[ot] = __builtin_amdgcn_mfma_f32_16x16x32_bf16(ah.v, bh.v, acc0[ot], 0, 0, 0);
        }
    }
    float crd[4][3];
    #pragma unroll
    for (int r = 0; r < 4; ++r) {
        const int n = wv * 16 + q * 4 + r;
        crd[r][0] = Abuf[n * 132 + 128];
        crd[r][1] = Abuf[n * 132 + 129];
        crd[r][2] = Abuf[n * 132 + 130];
    }
    #pragma unroll
    for (int ot = 0; ot < 8; ++ot) {
        const float4 wc = Wc0[ot * 16 + m];
        #pragma unroll
        for (int r = 0; r < 4; ++r) {
            const float v = acc0[ot][r] + wc.w + wc.x * crd[r][0] + wc.y * crd[r][1] + wc.z * crd[r][2];
            Bbuf[(wv * 16 + q * 4 + r) * 132 + ot * 16 + m] = fmaxf(v, 0.0f);
        }
    }
    __syncthreads();

    // layer 1: 128 -> 128
    f32x4 acc1[8];
    #pragma unroll
    for (int ot = 0; ot < 8; ++ot)
        #pragma unroll
        for (int r = 0; r < 4; ++r) acc1[ot][r] = 0.0f;
    #pragma unroll
    for (int ks = 0; ks < 4; ++ks) {
        float xv[8];
        *(float4*)&xv[0] = *(const float4*)&Bbuf[rowA * 132 + ks * 32 + q * 8];
        *(float4*)&xv[4] = *(const float4*)&Bbuf[rowA * 132 + ks * 32 + q * 8 + 4];
        SV8 ah;
        #pragma unroll
        for (int j = 0; j < 8; ++j) ah.u[j] = f2bf(xv[j]);
        #pragma unroll
        for (int ot = 0; ot < 8; ++ot) {
            SV8 bh;
            bh.v = *(const short8*)(W1h + (size_t)((ks * 8 + ot) * 64 + lane) * 8);
            acc1[ot] = __builtin_amdgcn_mfma_f32_16x16x32_bf16(ah.v, bh.v, acc1[ot], 0, 0, 0);
        }
    }
    __syncthreads();
    #pragma unroll
    for (int ot = 0; ot < 8; ++ot) {
        const float bb = b1[ot * 16 + m];
        #pragma unroll
        for (int r = 0; r < 4; ++r)
            Abuf[(wv * 16 + q * 4 + r) * 132 + ot * 16 + m] = fmaxf(acc1[ot][r] + bb, 0.0f);
    }
    __syncthreads();

    // layer 2: 128 -> 256, relu+max
    f32x4 acc2[16];
    #pragma unroll
    for (int ot = 0; ot < 16; ++ot)
        #pragma unroll
        for (int r = 0; r < 4; ++r) acc2[ot][r] = 0.0f;
    #pragma unroll
    for (int ks = 0; ks < 4; ++ks) {
        float xv[8];
        *(float4*)&xv[0] = *(const float4*)&Abuf[rowA * 132 + ks * 32 + q * 8];
        *(float4*)&xv[4] = *(const float4*)&Abuf[rowA * 132 + ks * 32 + q * 8 + 4];
        SV8 ah;
        #pragma unroll
        for (int j = 0; j < 8; ++j) ah.u[j] = f2bf(xv[j]);
        #pragma unroll
        for (int ot = 0; ot < 16; ++ot) {
            SV8 bh;
            bh.v = *(const short8*)(W2h + (size_t)((ks * 16 + ot) * 64 + lane) * 8);
            acc2[ot] = __builtin_amdgcn_mfma_f32_16x16x32_bf16(ah.v, bh.v, acc2[ot], 0, 0, 0);
        }
    }
    __syncthreads();
    #pragma unroll
    for (int ot = 0; ot < 16; ++ot) {
        const float bb = b2[ot * 16 + m];
        float mx = 0.0f;
        #pragma unroll
        for (int r = 0; r < 4; ++r) mx = fmaxf(mx, acc2[ot][r] + bb);
        Bbuf[(wv * 4 + q) * 256 + ot * 16 + m] = mx;
    }
    __syncthreads();
    {
        float v = Bbuf[t];
        #pragma unroll
        for (int rr = 1; rr < 16; ++rr) v = fmaxf(v, Bbuf[rr * 256 + t]);
        X3[(size_t)bs * 288 + 3 + t] = v;
    }
}

// =========== cooperative tail: g1 + g2 + g3(MAXOUT) + FC head ==============
// 256 blocks (1/CU, co-resident). Per-block instruction streams identical to
// the old gemm_mfma launches; grid.sync() replaces kernel boundaries.
__device__ __forceinline__ void gemm_tile4(const float* __restrict__ A, int AS,
                                           const ushort* __restrict__ Wh,
                                           const float* __restrict__ bias,
                                           float* __restrict__ C, int O,
                                           int KSTEPS, int rt, int bo,
                                           int lane, int wv, int m, int q) {
    const int rowA = rt * 64 + wv * 16 + m;
    const int OT = O >> 4;
    f32x4 acc[4];
    #pragma unroll
    for (int ot = 0; ot < 4; ++ot)
        #pragma unroll
        for (int r = 0; r < 4; ++r) acc[ot][r] = 0.0f;
    for (int ks = 0; ks < KSTEPS; ++ks) {
        float xv[8];
        *(float4*)&xv[0] = *(const float4*)&A[(size_t)rowA * AS + ks * 32 + q * 8];
        *(float4*)&xv[4] = *(const float4*)&A[(size_t)rowA * AS + ks * 32 + q * 8 + 4];
        SV8 ah;
        #pragma unroll
        for (int j = 0; j < 8; ++j) ah.u[j] = f2bf(xv[j]);
        #pragma unroll
        for (int ot = 0; ot < 4; ++ot) {
            const size_t wb = (size_t)((ks * OT + bo * 4 + ot) * 64 + lane) * 8;
            SV8 bh;
            bh.v = *(const short8*)(Wh + wb);
            acc[ot] = __builtin_amdgcn_mfma_f32_16x16x32_bf16(ah.v, bh.v, acc[ot], 0, 0, 0);
        }
    }
    #pragma unroll
    for (int ot = 0; ot < 4; ++ot) {
        const int col = (bo * 4 + ot) * 16 + m;
        const float bb = bias[col];
        #pragma unroll
        for (int r = 0; r < 4; ++r) {
            const int row = rt * 64 + wv * 16 + q * 4 + r;
            C[(size_t)row * O + col] = fmaxf(acc[ot][r] + bb, 0.0f);
        }
    }
}

__global__ __launch_bounds__(256)
void tail_coop_kernel(const float* __restrict__ X3,
                      const ushort* __restrict__ W0h, const float* __restrict__ b0,
                      const ushort* __restrict__ W1h, const float* __restrict__ b1,
                      const ushort* __restrict__ W2h, const float* __restrict__ b2,
                      float* __restrict__ Y1, float* __restrict__ Y2,
                      float* __restrict__ P3,
                      const float* __restrict__ f1w, const float* __restrict__ f1b,
                      const float* __restrict__ f2w, const float* __restrict__ f2b,
                      const float* __restrict__ f3w, const float* __restrict__ f3b,
                      float* __restrict__ out) {
    cg::grid_group grid = cg::this_grid();
    __shared__ float part[16][64];
    __shared__ __align__(16) float xb[1024];
    __shared__ __align__(16) float h1b[512];
    __shared__ __align__(16) float h2b[256];
    const int t = threadIdx.x, lane = t & 63, wv = t >> 6;
    const int m = lane & 15, q = lane >> 4;
    const int bid = blockIdx.x;
    const int rt = bid >> 2, bq4 = bid & 3;

    // phase 1: X3 (4096x288) -> Y1 (4096x256); same split as old g1 (64x4)
    gemm_tile4(X3, 288, W0h, b0, Y1, 256, 9, rt, bq4, lane, wv, m, q);
    grid.sync();

    // phase 2: Y1 -> Y2 (4096x512); old g2 was (64x8): 2 bo's per block
    #pragma unroll
    for (int j = 0; j < 2; ++j)
        gemm_tile4(Y1, 256, W1h, b1, Y2, 512, 8, rt, bq4 * 2 + j, lane, wv, m, q);
    grid.sync();

    // phase 3: Y2 -> P3 (64x1024 MAXOUT); old g3 was (64x16): 4 bo's per block
    for (int j = 0; j < 4; ++j) {
        const int bo = bq4 * 4 + j;
        f32x4 acc[4];
        #pragma unroll
        for (int ot = 0; ot < 4; ++ot)
            #pragma unroll
            for (int r = 0; r < 4; ++r) acc[ot][r] = 0.0f;
        const int rowA = rt * 64 + wv * 16 + m;
        for (int ks = 0; ks < 16; ++ks) {
            float xv[8];
            *(float4*)&xv[0] = *(const float4*)&Y2[(size_t)rowA * 512 + ks * 32 + q * 8];
            *(float4*)&xv[4] = *(const float4*)&Y2[(size_t)rowA * 512 + ks * 32 + q * 8 + 4];
            SV8 ah;
            #pragma unroll
            for (int jj = 0; jj < 8; ++jj) ah.u[jj] = f2bf(xv[jj]);
            #pragma unroll
            for (int ot = 0; ot < 4; ++ot) {
                const size_t wb = (size_t)((ks * 64 + bo * 4 + ot) * 64 + lane) * 8;
                SV8 bh;
                bh.v = *(const short8*)(W2h + wb);
                acc[ot] = __builtin_amdgcn_mfma_f32_16x16x32_bf16(ah.v, bh.v, acc[ot], 0, 0, 0);
            }
        }
        #pragma unroll
        for (int ot = 0; ot < 4; ++ot) {
            const float bb = b2[(bo * 4 + ot) * 16 + m];
            float mx = 0.0f;
            #pragma unroll
            for (int r = 0; r < 4; ++r) mx = fmaxf(mx, acc[ot][r] + bb);
            part[wv * 4 + q][ot * 16 + m] = mx;
        }
        __syncthreads();
        for (int o = t; o < 64; o += 256) {
            float v = part[0][o];
            #pragma unroll
            for (int rr = 1; rr < 16; ++rr) v = fmaxf(v, part[rr][o]);
            P3[(size_t)rt * 1024 + bo * 64 + o] = v;
        }
        __syncthreads();   // part reused next j
    }
    grid.sync();

    // phase 4: FC head, one block per batch (blocks 0..31)
    if (bid >= 32) return;
    const int b = bid;
    for (int i = t; i < 1024; i += 256)
        xb[i] = fmaxf(P3[(size_t)(2*b)*1024 + i], P3[(size_t)(2*b+1)*1024 + i]);
    __syncthreads();
    #pragma unroll
    for (int oo = 0; oo < 2; ++oo) {       // f1: 1024 -> 512
        const int o = t + oo * 256;
        const float4* wr = (const float4*)(f1w + (size_t)o * 1024);
        float s0 = 0, s1 = 0, s2 = 0, s3 = 0;
        for (int c = 0; c < 256; ++c) {
            const float4 w4 = wr[c];
            const float4 xv = *(const float4*)&xb[c * 4];
            s0 += w4.x * xv.x; s1 += w4.y * xv.y; s2 += w4.z * xv.z; s3 += w4.w * xv.w;
        }
        h1b[o] = fmaxf(f1b[o] + ((s0 + s1) + (s2 + s3)), 0.0f);
    }
    __syncthreads();
    {                                       // f2: 512 -> 256
        const float4* wr = (const float4*)(f2w + (size_t)t * 512);
        float s0 = 0, s1 = 0, s2 = 0, s3 = 0;
        for (int c = 0; c < 128; ++c) {
            const float4 w4 = wr[c];
            const float4 xv = *(const float4*)&h1b[c * 4];
            s0 += w4.x * xv.x; s1 += w4.y * xv.y; s2 += w4.z * xv.z; s3 += w4.w * xv.w;
        }
        h2b[t] = fmaxf(f2b[t] + ((s0 + s1) + (s2 + s3)), 0.0f);
    }
    __syncthreads();
    if (t < 6) {                            // f3: 256 -> 6
        const float4* wr = (const float4*)(f3w + (size_t)t * 256);
        float s0 = 0, s1 = 0, s2 = 0, s3 = 0;
        for (int c = 0; c < 64; ++c) {
            const float4 w4 = wr[c];
            const float4 xv = *(const float4*)&h2b[c * 4];
            s0 += w4.x * xv.x; s1 += w4.y * xv.y; s2 += w4.z * xv.z; s3 += w4.w * xv.w;
        }
        out[b * 6 + t] = f3b[t] + ((s0 + s1) + (s2 + s3));
    }
}

// ============================ launch =======================================
extern "C" void kernel_launch(void* const* d_in, const int* in_sizes, int n_in,
                              void* d_out, int out_size, void* d_ws, size_t ws_size,
                              hipStream_t stream) {
    const float* xyz  = (const float*)d_in[0];
    const float* s1w0 = (const float*)d_in[1];  const float* s1b0 = (const float*)d_in[2];
    const float* s1w1 = (const float*)d_in[3];  const float* s1b1 = (const float*)d_in[4];
    const float* s1w2 = (const float*)d_in[5];  const float* s1b2 = (const float*)d_in[6];
    const float* s2w0 = (const float*)d_in[7];  const float* s2b0 = (const float*)d_in[8];
    const float* s2w1 = (const float*)d_in[9];  const float* s2b1 = (const float*)d_in[10];
    const float* s2w2 = (const float*)d_in[11]; const float* s2b2 = (const float*)d_in[12];
    const float* s3w0 = (const float*)d_in[13]; const float* s3b0 = (const float*)d_in[14];
    const float* s3w1 = (const float*)d_in[15]; const float* s3b1 = (const float*)d_in[16];
    const float* s3w2 = (const float*)d_in[17]; const float* s3b2 = (const float*)d_in[18];
    const float* f1w  = (const float*)d_in[19]; const float* f1b  = (const float*)d_in[20];
    const float* f2w  = (const float*)d_in[21]; const float* f2b  = (const float*)d_in[22];
    const float* f3w  = (const float*)d_in[23]; const float* f3b  = (const float*)d_in[24];

    char* ws = (char*)d_ws;
    float* l1_xyz = (float*)(ws + 0);              // 32*512*3
    int*   gidx1  = (int*)  (ws + 196608);         // 32*512*32
    float* l1p    = (float*)(ws + 2293760);        // 32*512*128
    float* l2_xyz = (float*)(ws + 10682368);       // 32*128*3
    float* X3p    = (float*)(ws + 11780096);       // 4096*288 (zero-padded)
    const size_t PK = 16498688;                    // pack region (h-only)
    float4* Wc1   = (float4*)(ws + PK + 0);
    ushort* M1W1h = (ushort*)(ws + PK + 1024);
    ushort* M1W2h = (ushort*)(ws + PK + 17408);
    ushort* W0h   = (ushort*)(ws + PK + 50176);
    ushort* W1h   = (ushort*)(ws + PK + 115712);
    ushort* W2h   = (ushort*)(ws + PK + 181248);
    float4* Wc0   = (float4*)(ws + PK + 312320);
    ushort* S3W0h = (ushort*)(ws + PK + 314368);
    ushort* S3W1h = (ushort*)(ws + PK + 609280);
    ushort* S3W2h = (ushort*)(ws + PK + 1133568);
    float* Y1   = (float*)(ws + 19729408);         // 4096*256
    float* Y2   = (float*)(ws + 23923712);         // 4096*512
    float* P3   = (float*)(ws + 32312320);         // 64*1024 fp32 partial maxima

    // Stage 1 (fps1 on blocks 0..31, weight pack on blocks 32..)
    fps1_prep_kernel<<<3186, 256, 0, stream>>>(xyz, l1_xyz,
        s1w0, s1b0, Wc1, s1w1, M1W1h, s1w2, M1W2h,
        s3w0, S3W0h, s3w1, S3W1h, s3w2, S3W2h,
        s2w0, s2b0, Wc0, W0h, s2w1, W1h, s2w2, W2h);
    bq_kernel<4096, 32, true, 1024><<<1024, 1024, 0, stream>>>(
        (float)(0.2 * 0.2), xyz, l1_xyz, gidx1, 512);
    {
        dim3 g(257, 32);   // x==256 -> fps2 for batch y
        mlp1_kernel<<<g, 256, 0, stream>>>(xyz, l1_xyz, l2_xyz, gidx1,
            Wc1, M1W1h, s1b1, M1W2h, s1b2, l1p);
    }

    // Stage 2 (ball query inlined into mlp2)
    mlp2_kernel<<<4096, 256, 0, stream>>>(l1_xyz, l1p, l2_xyz,
        W0h, Wc0, W1h, s2b1, W2h, s2b2, X3p);

    // Stage 3 + FC head: one cooperative kernel (g1+g2+g3+fchead)
    {
        float* dout = (float*)d_out;
        void* args[] = {
            (void*)&X3p, (void*)&S3W0h, (void*)&s3b0,
            (void*)&S3W1h, (void*)&s3b1, (void*)&S3W2h, (void*)&s3b2,
            (void*)&Y1, (void*)&Y2, (void*)&P3,
            (void*)&f1w, (void*)&f1b, (void*)&f2w, (void*)&f2b,
            (void*)&f3w, (void*)&f3b, (void*)&dout
        };
        hipLaunchCooperativeKernel((const void*)tail_coop_kernel,
                                   dim3(256), dim3(256), args, 0, stream);
    }
    (void)in_sizes; (void)n_in; (void)out_size; (void)ws_size;
}

// Round 4
// 783.089 us; speedup vs baseline: 1.1522x; 1.1522x over previous
//
#include <hip/hip_runtime.h>
#include <hip/hip_bf16.h>

// ---------------------------------------------------------------------------
// PointNet++ critic forward. B=32, N=4096.
// R20 = R13 exactly (783us best; R18 fused3 and R19 coop-tail both reverted:
// -parallelism fusion +50us, coop launch/grid.sync +119us) plus TWO
// scheduling-only edits targeting the fps2-inside-mlp1 tail that R19's
// profile exposed (mlp1 row: occ 4%, mfma 1.2% -> long empty fps2 tail):
//   1. fps2 moved to blockIdx.x==0 (dispatched FIRST, overlaps the MLP
//      wavefront instead of starting after it drains)
//   2. s_setprio(1) around the fps selection loop (T5: protects the
//      latency-critical serial chain from MLP waves' issue pressure)
// No numerics change anywhere.
// ---------------------------------------------------------------------------

typedef __attribute__((ext_vector_type(8))) short short8;
typedef __attribute__((ext_vector_type(4))) float f32x4;
union SV8 { short8 v; ushort u[8]; };

__device__ __forceinline__ ushort f2bf(float x) {
    unsigned u = __float_as_uint(x);
    unsigned r = (u + 0x7fffu + ((u >> 16) & 1u)) >> 16;   // RNE
    return (ushort)r;
}

// ======================= DPP wave64 max-reduce (u64) =======================
template<int CTRL>
__device__ __forceinline__ unsigned long long dpp_mov_u64(unsigned long long x) {
    const int lo = (int)(unsigned)(x & 0xffffffffull);
    const int hi = (int)(unsigned)(x >> 32);
    const int nlo = __builtin_amdgcn_update_dpp(lo, lo, CTRL, 0xf, 0xf, false);
    const int nhi = __builtin_amdgcn_update_dpp(hi, hi, CTRL, 0xf, 0xf, false);
    return ((unsigned long long)(unsigned)nhi << 32) | (unsigned)nlo;
}

__device__ __forceinline__ unsigned long long wave_max_u64(unsigned long long x) {
    unsigned long long y;
    y = dpp_mov_u64<0x111>(x); if (y > x) x = y;   // row_shr:1
    y = dpp_mov_u64<0x112>(x); if (y > x) x = y;   // row_shr:2
    y = dpp_mov_u64<0x114>(x); if (y > x) x = y;   // row_shr:4
    y = dpp_mov_u64<0x118>(x); if (y > x) x = y;   // row_shr:8
    y = dpp_mov_u64<0x142>(x); if (y > x) x = y;   // row_bcast:15
    y = dpp_mov_u64<0x143>(x); if (y > x) x = y;   // row_bcast:31
    return x;
}

// ============================ FPS body (R12/R13) ===========================
template<int N, int S, int NT, bool CHW>
__device__ __forceinline__ void fps_body(const float* __restrict__ xyz,
                                         float* __restrict__ new_xyz,
                                         int b, int t, char* smem) {
    constexpr int P  = N / NT;
    constexpr int NW = NT / 64;
    float4* sxyz = (float4*)smem;
    unsigned long long* rv = (unsigned long long*)(smem + (size_t)N * 16);
    int* sfar = (int*)(smem + (size_t)N * 16 + 2 * NW * 8);
    float px[P], py[P], pz[P], dist[P];
    unsigned idc[P];
    if (CHW) {
        const float* base = xyz + (size_t)b * 3 * N;
        #pragma unroll
        for (int p = 0; p < P; ++p) {
            const int i = p * NT + t;
            px[p] = base[i]; py[p] = base[N + i]; pz[p] = base[2 * N + i];
            sxyz[i] = make_float4(px[p], py[p], pz[p], 0.0f);
        }
    } else {
        const float* base = xyz + (size_t)b * N * 3;
        #pragma unroll
        for (int p = 0; p < P; ++p) {
            const int i = p * NT + t;
            px[p] = base[i*3]; py[p] = base[i*3+1]; pz[p] = base[i*3+2];
            sxyz[i] = make_float4(px[p], py[p], pz[p], 0.0f);
        }
    }
    #pragma unroll
    for (int p = 0; p < P; ++p) { dist[p] = 1e10f; idc[p] = (unsigned)(N - 1 - (p * NT + t)); }
    __syncthreads();
    // latency-critical serial loop: favor these waves in CU issue arbitration
    __builtin_amdgcn_s_setprio(1);
    int far = 0;
    for (int j = 0; j < S; ++j) {
        if (t == 0) sfar[j] = far;           // LDS only — no VMEM in loop
        const float4 cen = sxyz[far];        // broadcast b128
        unsigned long long pk[P];
        #pragma unroll
        for (int p = 0; p < P; ++p) {
            const float dx = px[p] - cen.x, dy = py[p] - cen.y, dz = pz[p] - cen.z;
            // match reference rounding exactly: no FMA contraction
            const float d = __fadd_rn(__fadd_rn(__fmul_rn(dx, dx), __fmul_rn(dy, dy)), __fmul_rn(dz, dz));
            const float nd = fminf(dist[p], d);
            dist[p] = nd;
            pk[p] = ((unsigned long long)__float_as_uint(nd) << 32) | idc[p];
        }
        #pragma unroll
        for (int s = P / 2; s > 0; s >>= 1)
            #pragma unroll
            for (int k = 0; k < s; ++k)
                if (pk[k + s] > pk[k]) pk[k] = pk[k + s];
        unsigned long long best = wave_max_u64(pk[0]);
        if constexpr (NW > 1) {
            const int sl = (j & 1) * NW;     // parity slots: overwrite-safe
            if ((t & 63) == 63) rv[sl + (t >> 6)] = best;
            __syncthreads();
            unsigned long long bb = rv[sl];
            #pragma unroll
            for (int w = 1; w < NW; ++w) { const unsigned long long v = rv[sl + w]; if (v > bb) bb = v; }
            far = N - 1 - (int)(bb & 0xffffffffull);
        } else {
            far = N - 1 - __builtin_amdgcn_readlane((int)(best & 0xffffffffull), 63);
        }
    }
    __builtin_amdgcn_s_setprio(0);
    __syncthreads();
    float* out = new_xyz + (size_t)b * S * 3;
    for (int i = t; i < S; i += NT) {
        const float4 c = sxyz[sfar[i]];
        out[i*3+0] = c.x; out[i*3+1] = c.y; out[i*3+2] = c.z;
    }
}

// ==================== weight bf16 tile pack (h only) =======================
__device__ __forceinline__ void packg(const float* __restrict__ src,
                                      ushort* __restrict__ dh,
                                      int Ktot, int otiles, int cofs, int idx) {
    const int j = idx & 7, lane = (idx >> 3) & 63;
    const int ot = (idx >> 9) % otiles;
    const int ks = idx / (512 * otiles);
    const int m = lane & 15, q = lane >> 4;
    const int o = ot * 16 + m, c = cofs + ks * 32 + q * 8 + j;
    const float v = (c < Ktot) ? src[(size_t)o * Ktot + c] : 0.0f;
    dh[idx] = f2bf(v);
}

// ================= fps1 + weight pack, merged launch =======================
__global__ __launch_bounds__(256)
void fps1_prep_kernel(const float* __restrict__ xyz, float* __restrict__ l1xyz,
                 const float* s1w0, const float* s1b0, float4* Wc1,
                 const float* s1w1, ushort* M1W1h,
                 const float* s1w2, ushort* M1W2h,
                 const float* s3w0, ushort* S3W0h,
                 const float* s3w1, ushort* S3W1h,
                 const float* s3w2, ushort* S3W2h,
                 const float* s2w0, const float* s2b0, float4* Wc0,
                 ushort* W0h,
                 const float* s2w1, ushort* W1h,
                 const float* s2w2, ushort* W2h) {
    __shared__ __align__(16) char smem[4096 * 16 + 64 + 512 * 4];
    if (blockIdx.x < 32) {
        fps_body<4096, 512, 256, true>(xyz, l1xyz, blockIdx.x, threadIdx.x, smem);
        return;
    }
    int i = (blockIdx.x - 32) * 256 + threadIdx.x;
    if (i < 64)     { Wc1[i] = make_float4(s1w0[i*3], s1w0[i*3+1], s1w0[i*3+2], s1b0[i]); return; }  i -= 64;
    if (i < 4096)   { packg(s1w1, M1W1h,  64,  4, 0, i); return; }   i -= 4096;
    if (i < 8192)   { packg(s1w2, M1W2h,  64,  8, 0, i); return; }   i -= 8192;
    if (i < 73728)  { packg(s3w0, S3W0h, 259, 16, 0, i); return; }   i -= 73728;
    if (i < 131072) { packg(s3w1, S3W1h, 256, 32, 0, i); return; }   i -= 131072;
    if (i < 524288) { packg(s3w2, S3W2h, 512, 64, 0, i); return; }   i -= 524288;
    if (i < 16384)  { packg(s2w0, W0h, 131,  8, 3, i); return; }     i -= 16384;
    if (i < 16384)  { packg(s2w1, W1h, 128,  8, 0, i); return; }     i -= 16384;
    if (i < 32768)  { packg(s2w2, W2h, 128, 16, 0, i); return; }     i -= 32768;
    if (i < 128) {
        Wc0[i] = make_float4(s2w0[(size_t)i*131+0], s2w0[(size_t)i*131+1],
                             s2w0[(size_t)i*131+2], s2b0[i]);
    }
}

// ============================ Ball query ===================================
template<int N, int NS, bool CHW, int NT>
__global__ __launch_bounds__(NT)
void bq_kernel(float r2, const float* __restrict__ xyz, const float* __restrict__ cen,
               int* __restrict__ gidx, int S) {
    constexpr int WPB = NT / 64;
    __shared__ __align__(16) float4 sp[N];
    const int t = threadIdx.x, lane = t & 63, w = t >> 6;
    const int cen0 = blockIdx.x * WPB;
    const int b = cen0 / S;                     // WPB divides S -> same batch
    if (CHW) {
        const float* base = xyz + (size_t)b * 3 * N;
        for (int i = t; i < N; i += NT)
            sp[i] = make_float4(base[i], base[N + i], base[2 * N + i], 0.0f);
    } else {
        const float* base = xyz + (size_t)b * N * 3;
        for (int i = t; i < N; i += NT)
            sp[i] = make_float4(base[i*3], base[i*3+1], base[i*3+2], 0.0f);
    }
    __syncthreads();
    const int wid = cen0 + w;
    const float cx = cen[(size_t)wid*3+0], cy = cen[(size_t)wid*3+1], cz = cen[(size_t)wid*3+2];
    int* out = gidx + (size_t)wid * NS;
    int cnt = 0, first = -1;
    for (int b0 = 0; b0 < N; b0 += 64) {
        const float4 p = sp[b0 + lane];
        const float dx = p.x - cx, dy = p.y - cy, dz = p.z - cz;
        const float d = __fadd_rn(__fadd_rn(__fmul_rn(dx, dx), __fmul_rn(dy, dy)), __fmul_rn(dz, dz));
        const bool in = (d <= r2);
        const unsigned long long m = __ballot(in);
        if (first < 0 && m != 0ull) first = b0 + __ffsll((unsigned long long)m) - 1;
        const int pos = cnt + (int)__popcll(m & ((1ull << lane) - 1ull));
        if (in && pos < NS) out[pos] = b0 + lane;
        cnt += (int)__popcll(m);
        if (cnt >= NS) break;
    }
    if (cnt < NS)
        for (int k = cnt + lane; k < NS; k += 64) out[k] = first;
}

// ==================== MLP stage 1 (MFMA bf16) + fps2 merged ================
// fps2 at blockIdx.x==0 so it is dispatched FIRST (overlaps the MLP
// wavefront); MLP blocks handle s0 = (x-1)*2.
__global__ __launch_bounds__(256)
void mlp1_kernel(const float* __restrict__ xyz, const float* __restrict__ l1xyz,
                 float* __restrict__ l2xyz,
                 const int* __restrict__ gidx, const float4* __restrict__ Wc1,
                 const ushort* __restrict__ W1h, const float* __restrict__ b1,
                 const ushort* __restrict__ W2h, const float* __restrict__ b2,
                 float* __restrict__ l1p) {
    __shared__ __align__(16) char smem[64 * 68 * 4 * 2];   // 34816 B
    float* bufA = (float*)smem;
    float* bufB = (float*)(smem + 64 * 68 * 4);
    const int t = threadIdx.x, b = blockIdx.y;
    if (blockIdx.x == 0) {   // fps2 (dispatched first)
        fps_body<512, 128, 256, false>(l1xyz, l2xyz, b, t, smem);
        return;
    }
    const int s0 = (blockIdx.x - 1) * 2;
    {
        const int n = t >> 2, c = t & 3;
        const int s = s0 + (n >> 5);
        const int gi = gidx[((size_t)b * 512 + s) * 32 + (n & 31)];
        float v = 0.0f;
        if (c < 3) v = xyz[(size_t)b * 3 * 4096 + c * 4096 + gi] - l1xyz[((size_t)b * 512 + s) * 3 + c];
        bufB[n * 4 + c] = v;
    }
    __syncthreads();
    {   // layer0: 3 -> 64, exact fp32
        const int o = t & 63, ng = t >> 6;
        const float4 wc = Wc1[o];
        #pragma unroll
        for (int r = 0; r < 16; ++r) {
            const int n = ng * 16 + r;
            const float z = wc.w + wc.x * bufB[n*4] + wc.y * bufB[n*4+1] + wc.z * bufB[n*4+2];
            bufA[n * 68 + o] = fmaxf(z, 0.0f);
        }
    }
    const int lane = t & 63, wv = t >> 6;
    const int m = lane & 15, q = lane >> 4;
    const int rowA = wv * 16 + m;
    // layer1: 64 -> 64
    f32x4 acc1[4];
    #pragma unroll
    for (int ot = 0; ot < 4; ++ot)
        #pragma unroll
        for (int r = 0; r < 4; ++r) acc1[ot][r] = 0.0f;
    #pragma unroll
    for (int ks = 0; ks < 2; ++ks) {
        float xv[8];
        *(float4*)&xv[0] = *(const float4*)&bufA[rowA * 68 + ks * 32 + q * 8];
        *(float4*)&xv[4] = *(const float4*)&bufA[rowA * 68 + ks * 32 + q * 8 + 4];
        SV8 ah;
        #pragma unroll
        for (int j = 0; j < 8; ++j) ah.u[j] = f2bf(xv[j]);
        #pragma unroll
        for (int ot = 0; ot < 4; ++ot) {
            SV8 bh;
            bh.v = *(const short8*)(W1h + (size_t)((ks * 4 + ot) * 64 + lane) * 8);
            acc1[ot] = __builtin_amdgcn_mfma_f32_16x16x32_bf16(ah.v, bh.v, acc1[ot], 0, 0, 0);
        }
    }
    #pragma unroll
    for (int ot = 0; ot < 4; ++ot) {
        const float bb = b1[ot * 16 + m];
        #pragma unroll
        for (int r = 0; r < 4; ++r)
            bufB[(wv * 16 + q * 4 + r) * 68 + ot * 16 + m] = fmaxf(acc1[ot][r] + bb, 0.0f);
    }
    // layer2: 64 -> 128 + per-wave max
    f32x4 acc2[8];
    #pragma unroll
    for (int ot = 0; ot < 8; ++ot)
        #pragma unroll
        for (int r = 0; r < 4; ++r) acc2[ot][r] = 0.0f;
    #pragma unroll
    for (int ks = 0; ks < 2; ++ks) {
        float xv[8];
        *(float4*)&xv[0] = *(const float4*)&bufB[rowA * 68 + ks * 32 + q * 8];
        *(float4*)&xv[4] = *(const float4*)&bufB[rowA * 68 + ks * 32 + q * 8 + 4];
        SV8 ah;
        #pragma unroll
        for (int j = 0; j < 8; ++j) ah.u[j] = f2bf(xv[j]);
        #pragma unroll
        for (int ot = 0; ot < 8; ++ot) {
            SV8 bh;
            bh.v = *(const short8*)(W2h + (size_t)((ks * 8 + ot) * 64 + lane) * 8);
            acc2[ot] = __builtin_amdgcn_mfma_f32_16x16x32_bf16(ah.v, bh.v, acc2[ot], 0, 0, 0);
        }
    }
    __syncthreads();
    #pragma unroll
    for (int ot = 0; ot < 8; ++ot) {
        const float bb = b2[ot * 16 + m];
        float mx = 0.0f;
        #pragma unroll
        for (int r = 0; r < 4; ++r) mx = fmaxf(mx, acc2[ot][r] + bb);
        bufA[(wv * 4 + q) * 128 + ot * 16 + m] = mx;
    }
    __syncthreads();
    {
        const int half = t >> 7, o = t & 127;
        float v = bufA[(half * 8) * 128 + o];
        #pragma unroll
        for (int rr = 1; rr < 8; ++rr) v = fmaxf(v, bufA[(half * 8 + rr) * 128 + o]);
        l1p[((size_t)b * 512 + s0 + half) * 128 + o] = v;
    }
}

// ============================ MLP stage 2 (MFMA bf16) ======================
__global__ __launch_bounds__(256)
void mlp2_kernel(const float* __restrict__ l1xyz, const float* __restrict__ l1p,
                 const float* __restrict__ l2xyz, const int* __restrict__ gidx,
                 const ushort* __restrict__ W0h, const float4* __restrict__ Wc0,
                 const ushort* __restrict__ W1h, const float* __restrict__ b1,
                 const ushort* __restrict__ W2h, const float* __restrict__ b2,
                 float* __restrict__ X3) {
    __shared__ __align__(16) float Abuf[64 * 132];   // x / h2
    __shared__ __align__(16) float Bbuf[64 * 132];   // h1 / max-partials
    __shared__ int sg[64];
    const int t = threadIdx.x, bs = blockIdx.x, b = bs >> 7;
    if (t < 64) sg[t] = gidx[(size_t)bs * 64 + t];
    if (t < 3)  X3[(size_t)bs * 288 + t] = l2xyz[(size_t)bs * 3 + t];     // raw coords
    if (t >= 64 && t < 93) X3[(size_t)bs * 288 + 259 + (t - 64)] = 0.0f;  // zero pad
    __syncthreads();
    for (int i = t; i < 64 * 32; i += 256) {
        const int n = i >> 5, cc = i & 31;
        *(float4*)&Abuf[n * 132 + cc * 4] =
            *(const float4*)&l1p[((size_t)b * 512 + sg[n]) * 128 + cc * 4];
    }
    if (t < 192) {
        const int n = t / 3, c = t % 3;
        Abuf[n * 132 + 128 + c] =
            l1xyz[((size_t)b * 512 + sg[n]) * 3 + c] - l2xyz[(size_t)bs * 3 + c];
    }
    __syncthreads();
    const int lane = t & 63, wv = t >> 6;
    const int m = lane & 15, q = lane >> 4;
    const int rowA = wv * 16 + m;

    // layer 0: feats (K=128) MFMA + coords/bias epilogue
    f32x4 acc0[8];
    #pragma unroll
    for (int ot = 0; ot < 8; ++ot)
        #pragma unroll
        for (int r = 0; r < 4; ++r) acc0[ot][r] = 0.0f;
    #pragma unroll
    for (int ks = 0; ks < 4; ++ks) {
        float xv[8];
        *(float4*)&xv[0] = *(const float4*)&Abuf[rowA * 132 + ks * 32 + q * 8];
        *(float4*)&xv[4] = *(const float4*)&Abuf[rowA * 132 + ks * 32 + q * 8 + 4];
        SV8 ah;
        #pragma unroll
        for (int j = 0; j < 8; ++j) ah.u[j] = f2bf(xv[j]);
        #pragma unroll
        for (int ot = 0; ot < 8; ++ot) {
            SV8 bh;
            bh.v = *(const short8*)(W0h + (size_t)((ks * 8 + ot) * 64 + lane) * 8);
            acc0[ot] = __builtin_amdgcn_mfma_f32_16x16x32_bf16(ah.v, bh.v, acc0[ot], 0, 0, 0);
        }
    }
    float crd[4][3];
    #pragma unroll
    for (int r = 0; r < 4; ++r) {
        const int n = wv * 16 + q * 4 + r;
        crd[r][0] = Abuf[n * 132 + 128];
        crd[r][1] = Abuf[n * 132 + 129];
        crd[r][2] = Abuf[n * 132 + 130];
    }
    #pragma unroll
    for (int ot = 0; ot < 8; ++ot) {
        const float4 wc = Wc0[ot * 16 + m];
        #pragma unroll
        for (int r = 0; r < 4; ++r) {
            const float v = acc0[ot][r] + wc.w + wc.x * crd[r][0] + wc.y * crd[r][1] + wc.z * crd[r][2];
            Bbuf[(wv * 16 + q * 4 + r) * 132 + ot * 16 + m] = fmaxf(v, 0.0f);
        }
    }
    __syncthreads();

    // layer 1: 128 -> 128
    f32x4 acc1[8];
    #pragma unroll
    for (int ot = 0; ot < 8; ++ot)
        #pragma unroll
        for (int r = 0; r < 4; ++r) acc1[ot][r] = 0.0f;
    #pragma unroll
    for (int ks = 0; ks < 4; ++ks) {
        float xv[8];
        *(float4*)&xv[0] = *(const float4*)&Bbuf[rowA * 132 + ks * 32 + q * 8];
        *(float4*)&xv[4] = *(const float4*)&Bbuf[rowA * 132 + ks * 32 + q * 8 + 4];
        SV8 ah;
        #pragma unroll
        for (int j = 0; j < 8; ++j) ah.u[j] = f2bf(xv[j]);
        #pragma unroll
        for (int ot = 0; ot < 8; ++ot) {
            SV8 bh;
            bh.v = *(const short8*)(W1h + (size_t)((ks * 8 + ot) * 64 + lane) * 8);
            acc1[ot] = __builtin_amdgcn_mfma_f32_16x16x32_bf16(ah.v, bh.v, acc1[ot], 0, 0, 0);
        }
    }
    __syncthreads();
    #pragma unroll
    for (int ot = 0; ot < 8; ++ot) {
        const float bb = b1[ot * 16 + m];
        #pragma unroll
        for (int r = 0; r < 4; ++r)
            Abuf[(wv * 16 + q * 4 + r) * 132 + ot * 16 + m] = fmaxf(acc1[ot][r] + bb, 0.0f);
    }
    __syncthreads();

    // layer 2: 128 -> 256, relu+max
    f32x4 acc2[16];
    #pragma unroll
    for (int ot = 0; ot < 16; ++ot)
        #pragma unroll
        for (int r = 0; r < 4; ++r) acc2[ot][r] = 0.0f;
    #pragma unroll
    for (int ks = 0; ks < 4; ++ks) {
        float xv[8];
        *(float4*)&xv[0] = *(const float4*)&Abuf[rowA * 132 + ks * 32 + q * 8];
        *(float4*)&xv[4] = *(const float4*)&Abuf[rowA * 132 + ks * 32 + q * 8 + 4];
        SV8 ah;
        #pragma unroll
        for (int j = 0; j < 8; ++j) ah.u[j] = f2bf(xv[j]);
        #pragma unroll
        for (int ot = 0; ot < 16; ++ot) {
            SV8 bh;
            bh.v = *(const short8*)(W2h + (size_t)((ks * 16 + ot) * 64 + lane) * 8);
            acc2[ot] = __builtin_amdgcn_mfma_f32_16x16x32_bf16(ah.v, bh.v, acc2[ot], 0, 0, 0);
        }
    }
    __syncthreads();
    #pragma unroll
    for (int ot = 0; ot < 16; ++ot) {
        const float bb = b2[ot * 16 + m];
        float mx = 0.0f;
        #pragma unroll
        for (int r = 0; r < 4; ++r) mx = fmaxf(mx, acc2[ot][r] + bb);
        Bbuf[(wv * 4 + q) * 256 + ot * 16 + m] = mx;
    }
    __syncthreads();
    {
        float v = Bbuf[t];
        #pragma unroll
        for (int rr = 1; rr < 16; ++rr) v = fmaxf(v, Bbuf[rr * 256 + t]);
        X3[(size_t)bs * 288 + 3 + t] = v;
    }
}

// ===================== stage-3 GEMM via MFMA bf16 (no LDS A) ===============
template<int KSTEPS, int OTILES, bool MAXOUT>
__global__ __launch_bounds__(256)
void gemm_mfma_kernel(const float* __restrict__ A, int AS,
                      const ushort* __restrict__ Wh,
                      const float* __restrict__ bias, float* __restrict__ C, int O) {
    __shared__ float part[16][OTILES * 16];
    const int t = threadIdx.x, lane = t & 63, wv = t >> 6;
    const int m = lane & 15, q = lane >> 4;
    const int rowA = blockIdx.x * 64 + wv * 16 + m;
    const int bo = blockIdx.y, OT = O >> 4;
    f32x4 acc[OTILES];
    #pragma unroll
    for (int ot = 0; ot < OTILES; ++ot)
        #pragma unroll
        for (int r = 0; r < 4; ++r) acc[ot][r] = 0.0f;
    for (int ks = 0; ks < KSTEPS; ++ks) {
        float xv[8];
        *(float4*)&xv[0] = *(const float4*)&A[(size_t)rowA * AS + ks * 32 + q * 8];
        *(float4*)&xv[4] = *(const float4*)&A[(size_t)rowA * AS + ks * 32 + q * 8 + 4];
        SV8 ah;
        #pragma unroll
        for (int j = 0; j < 8; ++j) ah.u[j] = f2bf(xv[j]);
        #pragma unroll
        for (int ot = 0; ot < OTILES; ++ot) {
            const size_t wb = (size_t)((ks * OT + bo * OTILES + ot) * 64 + lane) * 8;
            SV8 bh;
            bh.v = *(const short8*)(Wh + wb);
            acc[ot] = __builtin_amdgcn_mfma_f32_16x16x32_bf16(ah.v, bh.v, acc[ot], 0, 0, 0);
        }
    }
    if (!MAXOUT) {
        #pragma unroll
        for (int ot = 0; ot < OTILES; ++ot) {
            const int col = (bo * OTILES + ot) * 16 + m;
            const float bb = bias[col];
            #pragma unroll
            for (int r = 0; r < 4; ++r) {
                const int row = blockIdx.x * 64 + wv * 16 + q * 4 + r;
                C[(size_t)row * O + col] = fmaxf(acc[ot][r] + bb, 0.0f);
            }
        }
    } else {
        #pragma unroll
        for (int ot = 0; ot < OTILES; ++ot) {
            const int col = (bo * OTILES + ot) * 16 + m;
            const float bb = bias[col];
            float mx = 0.0f;
            #pragma unroll
            for (int r = 0; r < 4; ++r) mx = fmaxf(mx, acc[ot][r] + bb);
            part[wv * 4 + q][ot * 16 + m] = mx;
        }
        __syncthreads();
        for (int o = t; o < OTILES * 16; o += 256) {
            float v = part[0][o];
            #pragma unroll
            for (int rr = 1; rr < 16; ++rr) v = fmaxf(v, part[rr][o]);
            C[(size_t)blockIdx.x * O + bo * OTILES * 16 + o] = v;
        }
    }
}

// ================= fused FC head (P3 row-max + 3 layers, fp32) =============
__global__ __launch_bounds__(256)
void fchead_kernel(const float* __restrict__ P3,
                   const float* __restrict__ f1w, const float* __restrict__ f1b,
                   const float* __restrict__ f2w, const float* __restrict__ f2b,
                   const float* __restrict__ f3w, const float* __restrict__ f3b,
                   float* __restrict__ out) {
    __shared__ __align__(16) float x[1024];
    __shared__ __align__(16) float h1[512];
    __shared__ __align__(16) float h2[256];
    const int t = threadIdx.x, b = blockIdx.x;
    for (int i = t; i < 1024; i += 256)
        x[i] = fmaxf(P3[(size_t)(2*b)*1024 + i], P3[(size_t)(2*b+1)*1024 + i]);
    __syncthreads();
    #pragma unroll
    for (int oo = 0; oo < 2; ++oo) {       // f1: 1024 -> 512
        const int o = t + oo * 256;
        const float4* wr = (const float4*)(f1w + (size_t)o * 1024);
        float s0 = 0, s1 = 0, s2 = 0, s3 = 0;
        for (int c = 0; c < 256; ++c) {
            const float4 w4 = wr[c];
            const float4 xv = *(const float4*)&x[c * 4];
            s0 += w4.x * xv.x; s1 += w4.y * xv.y; s2 += w4.z * xv.z; s3 += w4.w * xv.w;
        }
        h1[o] = fmaxf(f1b[o] + ((s0 + s1) + (s2 + s3)), 0.0f);
    }
    __syncthreads();
    {                                       // f2: 512 -> 256
        const float4* wr = (const float4*)(f2w + (size_t)t * 512);
        float s0 = 0, s1 = 0, s2 = 0, s3 = 0;
        for (int c = 0; c < 128; ++c) {
            const float4 w4 = wr[c];
            const float4 xv = *(const float4*)&h1[c * 4];
            s0 += w4.x * xv.x; s1 += w4.y * xv.y; s2 += w4.z * xv.z; s3 += w4.w * xv.w;
        }
        h2[t] = fmaxf(f2b[t] + ((s0 + s1) + (s2 + s3)), 0.0f);
    }
    __syncthreads();
    if (t < 6) {                            // f3: 256 -> 6
        const float4* wr = (const float4*)(f3w + (size_t)t * 256);
        float s0 = 0, s1 = 0, s2 = 0, s3 = 0;
        for (int c = 0; c < 64; ++c) {
            const float4 w4 = wr[c];
            const float4 xv = *(const float4*)&h2[c * 4];
            s0 += w4.x * xv.x; s1 += w4.y * xv.y; s2 += w4.z * xv.z; s3 += w4.w * xv.w;
        }
        out[b * 6 + t] = f3b[t] + ((s0 + s1) + (s2 + s3));
    }
}

// ============================ launch =======================================
extern "C" void kernel_launch(void* const* d_in, const int* in_sizes, int n_in,
                              void* d_out, int out_size, void* d_ws, size_t ws_size,
                              hipStream_t stream) {
    const float* xyz  = (const float*)d_in[0];
    const float* s1w0 = (const float*)d_in[1];  const float* s1b0 = (const float*)d_in[2];
    const float* s1w1 = (const float*)d_in[3];  const float* s1b1 = (const float*)d_in[4];
    const float* s1w2 = (const float*)d_in[5];  const float* s1b2 = (const float*)d_in[6];
    const float* s2w0 = (const float*)d_in[7];  const float* s2b0 = (const float*)d_in[8];
    const float* s2w1 = (const float*)d_in[9];  const float* s2b1 = (const float*)d_in[10];
    const float* s2w2 = (const float*)d_in[11]; const float* s2b2 = (const float*)d_in[12];
    const float* s3w0 = (const float*)d_in[13]; const float* s3b0 = (const float*)d_in[14];
    const float* s3w1 = (const float*)d_in[15]; const float* s3b1 = (const float*)d_in[16];
    const float* s3w2 = (const float*)d_in[17]; const float* s3b2 = (const float*)d_in[18];
    const float* f1w  = (const float*)d_in[19]; const float* f1b  = (const float*)d_in[20];
    const float* f2w  = (const float*)d_in[21]; const float* f2b  = (const float*)d_in[22];
    const float* f3w  = (const float*)d_in[23]; const float* f3b  = (const float*)d_in[24];

    char* ws = (char*)d_ws;
    float* l1_xyz = (float*)(ws + 0);              // 32*512*3
    int*   gidx1  = (int*)  (ws + 196608);         // 32*512*32
    float* l1p    = (float*)(ws + 2293760);        // 32*512*128
    float* l2_xyz = (float*)(ws + 10682368);       // 32*128*3
    int*   gidx2  = (int*)  (ws + 10731520);       // 32*128*64
    float* X3p    = (float*)(ws + 11780096);       // 4096*288 (zero-padded)
    const size_t PK = 16498688;                    // pack region (h-only)
    float4* Wc1   = (float4*)(ws + PK + 0);
    ushort* M1W1h = (ushort*)(ws + PK + 1024);
    ushort* M1W2h = (ushort*)(ws + PK + 17408);
    ushort* W0h   = (ushort*)(ws + PK + 50176);
    ushort* W1h   = (ushort*)(ws + PK + 115712);
    ushort* W2h   = (ushort*)(ws + PK + 181248);
    float4* Wc0   = (float4*)(ws + PK + 312320);
    ushort* S3W0h = (ushort*)(ws + PK + 314368);
    ushort* S3W1h = (ushort*)(ws + PK + 609280);
    ushort* S3W2h = (ushort*)(ws + PK + 1133568);
    float* Y1   = (float*)(ws + 19729408);         // 4096*256
    float* Y2   = (float*)(ws + 23923712);         // 4096*512
    float* P3   = (float*)(ws + 32312320);         // 64*1024 fp32 partial maxima

    // Stage 1 (fps1 on blocks 0..31, weight pack on blocks 32..)
    fps1_prep_kernel<<<3186, 256, 0, stream>>>(xyz, l1_xyz,
        s1w0, s1b0, Wc1, s1w1, M1W1h, s1w2, M1W2h,
        s3w0, S3W0h, s3w1, S3W1h, s3w2, S3W2h,
        s2w0, s2b0, Wc0, W0h, s2w1, W1h, s2w2, W2h);
    bq_kernel<4096, 32, true, 1024><<<1024, 1024, 0, stream>>>(
        (float)(0.2 * 0.2), xyz, l1_xyz, gidx1, 512);
    {
        dim3 g(257, 32);   // x==0 -> fps2 for batch y (dispatched first)
        mlp1_kernel<<<g, 256, 0, stream>>>(xyz, l1_xyz, l2_xyz, gidx1,
            Wc1, M1W1h, s1b1, M1W2h, s1b2, l1p);
    }

    // Stage 2
    bq_kernel<512, 64, false, 1024><<<256, 1024, 0, stream>>>(
        (float)(0.4 * 0.4), l1_xyz, l2_xyz, gidx2, 128);
    mlp2_kernel<<<4096, 256, 0, stream>>>(l1_xyz, l1p, l2_xyz, gidx2,
        W0h, Wc0, W1h, s2b1, W2h, s2b2, X3p);

    // Stage 3 (bf16 MFMA GEMMs; OTILES=4 everywhere = R13 schedule)
    {
        dim3 g1(64, 4);
        gemm_mfma_kernel<9,  4, false><<<g1, 256, 0, stream>>>(X3p, 288, S3W0h, s3b0, Y1, 256);
        dim3 g2(64, 8);
        gemm_mfma_kernel<8,  4, false><<<g2, 256, 0, stream>>>(Y1, 256, S3W1h, s3b1, Y2, 512);
        dim3 g3(64, 16);
        gemm_mfma_kernel<16, 4, true ><<<g3, 256, 0, stream>>>(Y2, 512, S3W2h, s3b2, P3, 1024);
    }

    // Fused FC head (row-max of P3 + 1024->512->256->6)
    fchead_kernel<<<32, 256, 0, stream>>>(P3, f1w, f1b, f2w, f2b, f3w, f3b, (float*)d_out);
    (void)in_sizes; (void)n_in; (void)out_size; (void)ws_size;
}

// Round 5
// 750.926 us; speedup vs baseline: 1.2016x; 1.0428x over previous
//
#include <hip/hip_runtime.h>
#include <hip/hip_bf16.h>

// ---------------------------------------------------------------------------
// PointNet++ critic forward. B=32, N=4096.
// R21 = R13 + (a) CORRECT fps2 front-load: mlp1 grid swapped to (32,257),
// x=batch y=role, so fps2 blocks are linear indices 0..31 (R20's x==0 edit
// was botched: with g(257,32) batch-31 fps2 sat at linear 7967/8224 — the
// dispatch-order hypothesis was never tested); (b) inline bq2 in mlp2
// (numerically verified in R19's passing run; removes a dispatch + gidx2
// round-trip; LDS 76KB -> still 2 blocks/CU). fps = R13 scalar form +
// neutral setprio. 9 -> 8 dispatches.
// ---------------------------------------------------------------------------

typedef __attribute__((ext_vector_type(8))) short short8;
typedef __attribute__((ext_vector_type(4))) float f32x4;
union SV8 { short8 v; ushort u[8]; };

__device__ __forceinline__ ushort f2bf(float x) {
    unsigned u = __float_as_uint(x);
    unsigned r = (u + 0x7fffu + ((u >> 16) & 1u)) >> 16;   // RNE
    return (ushort)r;
}

// ======================= DPP wave64 max-reduce (u64) =======================
template<int CTRL>
__device__ __forceinline__ unsigned long long dpp_mov_u64(unsigned long long x) {
    const int lo = (int)(unsigned)(x & 0xffffffffull);
    const int hi = (int)(unsigned)(x >> 32);
    const int nlo = __builtin_amdgcn_update_dpp(lo, lo, CTRL, 0xf, 0xf, false);
    const int nhi = __builtin_amdgcn_update_dpp(hi, hi, CTRL, 0xf, 0xf, false);
    return ((unsigned long long)(unsigned)nhi << 32) | (unsigned)nlo;
}

__device__ __forceinline__ unsigned long long wave_max_u64(unsigned long long x) {
    unsigned long long y;
    y = dpp_mov_u64<0x111>(x); if (y > x) x = y;   // row_shr:1
    y = dpp_mov_u64<0x112>(x); if (y > x) x = y;   // row_shr:2
    y = dpp_mov_u64<0x114>(x); if (y > x) x = y;   // row_shr:4
    y = dpp_mov_u64<0x118>(x); if (y > x) x = y;   // row_shr:8
    y = dpp_mov_u64<0x142>(x); if (y > x) x = y;   // row_bcast:15
    y = dpp_mov_u64<0x143>(x); if (y > x) x = y;   // row_bcast:31
    return x;
}

// ============================ FPS body (R12/R13) ===========================
template<int N, int S, int NT, bool CHW>
__device__ __forceinline__ void fps_body(const float* __restrict__ xyz,
                                         float* __restrict__ new_xyz,
                                         int b, int t, char* smem) {
    constexpr int P  = N / NT;
    constexpr int NW = NT / 64;
    float4* sxyz = (float4*)smem;
    unsigned long long* rv = (unsigned long long*)(smem + (size_t)N * 16);
    int* sfar = (int*)(smem + (size_t)N * 16 + 2 * NW * 8);
    float px[P], py[P], pz[P], dist[P];
    unsigned idc[P];
    if (CHW) {
        const float* base = xyz + (size_t)b * 3 * N;
        #pragma unroll
        for (int p = 0; p < P; ++p) {
            const int i = p * NT + t;
            px[p] = base[i]; py[p] = base[N + i]; pz[p] = base[2 * N + i];
            sxyz[i] = make_float4(px[p], py[p], pz[p], 0.0f);
        }
    } else {
        const float* base = xyz + (size_t)b * N * 3;
        #pragma unroll
        for (int p = 0; p < P; ++p) {
            const int i = p * NT + t;
            px[p] = base[i*3]; py[p] = base[i*3+1]; pz[p] = base[i*3+2];
            sxyz[i] = make_float4(px[p], py[p], pz[p], 0.0f);
        }
    }
    #pragma unroll
    for (int p = 0; p < P; ++p) { dist[p] = 1e10f; idc[p] = (unsigned)(N - 1 - (p * NT + t)); }
    __syncthreads();
    // latency-critical serial loop: favor these waves in CU issue arbitration
    __builtin_amdgcn_s_setprio(1);
    int far = 0;
    for (int j = 0; j < S; ++j) {
        if (t == 0) sfar[j] = far;           // LDS only — no VMEM in loop
        const float4 cen = sxyz[far];        // broadcast b128
        unsigned long long pk[P];
        #pragma unroll
        for (int p = 0; p < P; ++p) {
            const float dx = px[p] - cen.x, dy = py[p] - cen.y, dz = pz[p] - cen.z;
            // match reference rounding exactly: no FMA contraction
            const float d = __fadd_rn(__fadd_rn(__fmul_rn(dx, dx), __fmul_rn(dy, dy)), __fmul_rn(dz, dz));
            const float nd = fminf(dist[p], d);
            dist[p] = nd;
            pk[p] = ((unsigned long long)__float_as_uint(nd) << 32) | idc[p];
        }
        #pragma unroll
        for (int s = P / 2; s > 0; s >>= 1)
            #pragma unroll
            for (int k = 0; k < s; ++k)
                if (pk[k + s] > pk[k]) pk[k] = pk[k + s];
        unsigned long long best = wave_max_u64(pk[0]);
        if constexpr (NW > 1) {
            const int sl = (j & 1) * NW;     // parity slots: overwrite-safe
            if ((t & 63) == 63) rv[sl + (t >> 6)] = best;
            __syncthreads();
            unsigned long long bb = rv[sl];
            #pragma unroll
            for (int w = 1; w < NW; ++w) { const unsigned long long v = rv[sl + w]; if (v > bb) bb = v; }
            far = N - 1 - (int)(bb & 0xffffffffull);
        } else {
            far = N - 1 - __builtin_amdgcn_readlane((int)(best & 0xffffffffull), 63);
        }
    }
    __builtin_amdgcn_s_setprio(0);
    __syncthreads();
    float* out = new_xyz + (size_t)b * S * 3;
    for (int i = t; i < S; i += NT) {
        const float4 c = sxyz[sfar[i]];
        out[i*3+0] = c.x; out[i*3+1] = c.y; out[i*3+2] = c.z;
    }
}

// ==================== weight bf16 tile pack (h only) =======================
__device__ __forceinline__ void packg(const float* __restrict__ src,
                                      ushort* __restrict__ dh,
                                      int Ktot, int otiles, int cofs, int idx) {
    const int j = idx & 7, lane = (idx >> 3) & 63;
    const int ot = (idx >> 9) % otiles;
    const int ks = idx / (512 * otiles);
    const int m = lane & 15, q = lane >> 4;
    const int o = ot * 16 + m, c = cofs + ks * 32 + q * 8 + j;
    const float v = (c < Ktot) ? src[(size_t)o * Ktot + c] : 0.0f;
    dh[idx] = f2bf(v);
}

// ================= fps1 + weight pack, merged launch =======================
__global__ __launch_bounds__(256)
void fps1_prep_kernel(const float* __restrict__ xyz, float* __restrict__ l1xyz,
                 const float* s1w0, const float* s1b0, float4* Wc1,
                 const float* s1w1, ushort* M1W1h,
                 const float* s1w2, ushort* M1W2h,
                 const float* s3w0, ushort* S3W0h,
                 const float* s3w1, ushort* S3W1h,
                 const float* s3w2, ushort* S3W2h,
                 const float* s2w0, const float* s2b0, float4* Wc0,
                 ushort* W0h,
                 const float* s2w1, ushort* W1h,
                 const float* s2w2, ushort* W2h) {
    __shared__ __align__(16) char smem[4096 * 16 + 64 + 512 * 4];
    if (blockIdx.x < 32) {
        fps_body<4096, 512, 256, true>(xyz, l1xyz, blockIdx.x, threadIdx.x, smem);
        return;
    }
    int i = (blockIdx.x - 32) * 256 + threadIdx.x;
    if (i < 64)     { Wc1[i] = make_float4(s1w0[i*3], s1w0[i*3+1], s1w0[i*3+2], s1b0[i]); return; }  i -= 64;
    if (i < 4096)   { packg(s1w1, M1W1h,  64,  4, 0, i); return; }   i -= 4096;
    if (i < 8192)   { packg(s1w2, M1W2h,  64,  8, 0, i); return; }   i -= 8192;
    if (i < 73728)  { packg(s3w0, S3W0h, 259, 16, 0, i); return; }   i -= 73728;
    if (i < 131072) { packg(s3w1, S3W1h, 256, 32, 0, i); return; }   i -= 131072;
    if (i < 524288) { packg(s3w2, S3W2h, 512, 64, 0, i); return; }   i -= 524288;
    if (i < 16384)  { packg(s2w0, W0h, 131,  8, 3, i); return; }     i -= 16384;
    if (i < 16384)  { packg(s2w1, W1h, 128,  8, 0, i); return; }     i -= 16384;
    if (i < 32768)  { packg(s2w2, W2h, 128, 16, 0, i); return; }     i -= 32768;
    if (i < 128) {
        Wc0[i] = make_float4(s2w0[(size_t)i*131+0], s2w0[(size_t)i*131+1],
                             s2w0[(size_t)i*131+2], s2b0[i]);
    }
}

// ============================ Ball query (stage 1) =========================
template<int N, int NS, bool CHW, int NT>
__global__ __launch_bounds__(NT)
void bq_kernel(float r2, const float* __restrict__ xyz, const float* __restrict__ cen,
               int* __restrict__ gidx, int S) {
    constexpr int WPB = NT / 64;
    __shared__ __align__(16) float4 sp[N];
    const int t = threadIdx.x, lane = t & 63, w = t >> 6;
    const int cen0 = blockIdx.x * WPB;
    const int b = cen0 / S;                     // WPB divides S -> same batch
    if (CHW) {
        const float* base = xyz + (size_t)b * 3 * N;
        for (int i = t; i < N; i += NT)
            sp[i] = make_float4(base[i], base[N + i], base[2 * N + i], 0.0f);
    } else {
        const float* base = xyz + (size_t)b * N * 3;
        for (int i = t; i < N; i += NT)
            sp[i] = make_float4(base[i*3], base[i*3+1], base[i*3+2], 0.0f);
    }
    __syncthreads();
    const int wid = cen0 + w;
    const float cx = cen[(size_t)wid*3+0], cy = cen[(size_t)wid*3+1], cz = cen[(size_t)wid*3+2];
    int* out = gidx + (size_t)wid * NS;
    int cnt = 0, first = -1;
    for (int b0 = 0; b0 < N; b0 += 64) {
        const float4 p = sp[b0 + lane];
        const float dx = p.x - cx, dy = p.y - cy, dz = p.z - cz;
        const float d = __fadd_rn(__fadd_rn(__fmul_rn(dx, dx), __fmul_rn(dy, dy)), __fmul_rn(dz, dz));
        const bool in = (d <= r2);
        const unsigned long long m = __ballot(in);
        if (first < 0 && m != 0ull) first = b0 + __ffsll((unsigned long long)m) - 1;
        const int pos = cnt + (int)__popcll(m & ((1ull << lane) - 1ull));
        if (in && pos < NS) out[pos] = b0 + lane;
        cnt += (int)__popcll(m);
        if (cnt >= NS) break;
    }
    if (cnt < NS)
        for (int k = cnt + lane; k < NS; k += 64) out[k] = first;
}

// ==================== MLP stage 1 (MFMA bf16) + fps2 merged ================
// Grid (32, 257): x = batch, y = role. y==0 -> fps2; linear dispatch order
// is x-fastest, so the 32 fps2 blocks are indices 0..31 — ALL dispatched
// before any MLP block (the point of this round).
__global__ __launch_bounds__(256)
void mlp1_kernel(const float* __restrict__ xyz, const float* __restrict__ l1xyz,
                 float* __restrict__ l2xyz,
                 const int* __restrict__ gidx, const float4* __restrict__ Wc1,
                 const ushort* __restrict__ W1h, const float* __restrict__ b1,
                 const ushort* __restrict__ W2h, const float* __restrict__ b2,
                 float* __restrict__ l1p) {
    __shared__ __align__(16) char smem[64 * 68 * 4 * 2];   // 34816 B
    float* bufA = (float*)smem;
    float* bufB = (float*)(smem + 64 * 68 * 4);
    const int t = threadIdx.x, b = blockIdx.x;
    if (blockIdx.y == 0) {   // fps2 (linear blocks 0..31: truly first)
        fps_body<512, 128, 256, false>(l1xyz, l2xyz, b, t, smem);
        return;
    }
    const int s0 = (blockIdx.y - 1) * 2;
    {
        const int n = t >> 2, c = t & 3;
        const int s = s0 + (n >> 5);
        const int gi = gidx[((size_t)b * 512 + s) * 32 + (n & 31)];
        float v = 0.0f;
        if (c < 3) v = xyz[(size_t)b * 3 * 4096 + c * 4096 + gi] - l1xyz[((size_t)b * 512 + s) * 3 + c];
        bufB[n * 4 + c] = v;
    }
    __syncthreads();
    {   // layer0: 3 -> 64, exact fp32
        const int o = t & 63, ng = t >> 6;
        const float4 wc = Wc1[o];
        #pragma unroll
        for (int r = 0; r < 16; ++r) {
            const int n = ng * 16 + r;
            const float z = wc.w + wc.x * bufB[n*4] + wc.y * bufB[n*4+1] + wc.z * bufB[n*4+2];
            bufA[n * 68 + o] = fmaxf(z, 0.0f);
        }
    }
    const int lane = t & 63, wv = t >> 6;
    const int m = lane & 15, q = lane >> 4;
    const int rowA = wv * 16 + m;
    // layer1: 64 -> 64
    f32x4 acc1[4];
    #pragma unroll
    for (int ot = 0; ot < 4; ++ot)
        #pragma unroll
        for (int r = 0; r < 4; ++r) acc1[ot][r] = 0.0f;
    #pragma unroll
    for (int ks = 0; ks < 2; ++ks) {
        float xv[8];
        *(float4*)&xv[0] = *(const float4*)&bufA[rowA * 68 + ks * 32 + q * 8];
        *(float4*)&xv[4] = *(const float4*)&bufA[rowA * 68 + ks * 32 + q * 8 + 4];
        SV8 ah;
        #pragma unroll
        for (int j = 0; j < 8; ++j) ah.u[j] = f2bf(xv[j]);
        #pragma unroll
        for (int ot = 0; ot < 4; ++ot) {
            SV8 bh;
            bh.v = *(const short8*)(W1h + (size_t)((ks * 4 + ot) * 64 + lane) * 8);
            acc1[ot] = __builtin_amdgcn_mfma_f32_16x16x32_bf16(ah.v, bh.v, acc1[ot], 0, 0, 0);
        }
    }
    #pragma unroll
    for (int ot = 0; ot < 4; ++ot) {
        const float bb = b1[ot * 16 + m];
        #pragma unroll
        for (int r = 0; r < 4; ++r)
            bufB[(wv * 16 + q * 4 + r) * 68 + ot * 16 + m] = fmaxf(acc1[ot][r] + bb, 0.0f);
    }
    // layer2: 64 -> 128 + per-wave max
    f32x4 acc2[8];
    #pragma unroll
    for (int ot = 0; ot < 8; ++ot)
        #pragma unroll
        for (int r = 0; r < 4; ++r) acc2[ot][r] = 0.0f;
    #pragma unroll
    for (int ks = 0; ks < 2; ++ks) {
        float xv[8];
        *(float4*)&xv[0] = *(const float4*)&bufB[rowA * 68 + ks * 32 + q * 8];
        *(float4*)&xv[4] = *(const float4*)&bufB[rowA * 68 + ks * 32 + q * 8 + 4];
        SV8 ah;
        #pragma unroll
        for (int j = 0; j < 8; ++j) ah.u[j] = f2bf(xv[j]);
        #pragma unroll
        for (int ot = 0; ot < 8; ++ot) {
            SV8 bh;
            bh.v = *(const short8*)(W2h + (size_t)((ks * 8 + ot) * 64 + lane) * 8);
            acc2[ot] = __builtin_amdgcn_mfma_f32_16x16x32_bf16(ah.v, bh.v, acc2[ot], 0, 0, 0);
        }
    }
    __syncthreads();
    #pragma unroll
    for (int ot = 0; ot < 8; ++ot) {
        const float bb = b2[ot * 16 + m];
        float mx = 0.0f;
        #pragma unroll
        for (int r = 0; r < 4; ++r) mx = fmaxf(mx, acc2[ot][r] + bb);
        bufA[(wv * 4 + q) * 128 + ot * 16 + m] = mx;
    }
    __syncthreads();
    {
        const int half = t >> 7, o = t & 127;
        float v = bufA[(half * 8) * 128 + o];
        #pragma unroll
        for (int rr = 1; rr < 8; ++rr) v = fmaxf(v, bufA[(half * 8 + rr) * 128 + o]);
        l1p[((size_t)b * 512 + s0 + half) * 128 + o] = v;
    }
}

// ============== MLP stage 2 (MFMA bf16) with INLINE ball query =============
// (verified numerically in R19's passing run)
__global__ __launch_bounds__(256)
void mlp2_kernel(const float* __restrict__ l1xyz, const float* __restrict__ l1p,
                 const float* __restrict__ l2xyz,
                 const ushort* __restrict__ W0h, const float4* __restrict__ Wc0,
                 const ushort* __restrict__ W1h, const float* __restrict__ b1,
                 const ushort* __restrict__ W2h, const float* __restrict__ b2,
                 float* __restrict__ X3) {
    __shared__ __align__(16) float Abuf[64 * 132];   // x / h2
    __shared__ __align__(16) float Bbuf[64 * 132];   // h1 / max-partials
    __shared__ int sg[64];
    __shared__ __align__(16) float4 sp4[512];        // batch's 512 l1 points
    const int t = threadIdx.x, bs = blockIdx.x, b = bs >> 7;
    {   // stage the batch's 512 points (row-major l1xyz)
        const float* base = l1xyz + (size_t)b * 512 * 3;
        for (int i = t; i < 512; i += 256)
            sp4[i] = make_float4(base[i*3], base[i*3+1], base[i*3+2], 0.0f);
    }
    if (t < 3)  X3[(size_t)bs * 288 + t] = l2xyz[(size_t)bs * 3 + t];     // raw coords
    if (t >= 64 && t < 93) X3[(size_t)bs * 288 + 259 + (t - 64)] = 0.0f;  // zero pad
    __syncthreads();
    if (t < 64) {   // inline ball query for this centroid (wave 0) -> sg
        const float r2 = (float)(0.4 * 0.4);
        const float cx = l2xyz[(size_t)bs*3+0], cy = l2xyz[(size_t)bs*3+1], cz = l2xyz[(size_t)bs*3+2];
        int cnt = 0, first = -1;
        for (int b0 = 0; b0 < 512; b0 += 64) {
            const float4 p = sp4[b0 + t];
            const float dx = p.x - cx, dy = p.y - cy, dz = p.z - cz;
            const float d = __fadd_rn(__fadd_rn(__fmul_rn(dx, dx), __fmul_rn(dy, dy)), __fmul_rn(dz, dz));
            const bool in = (d <= r2);
            const unsigned long long mm = __ballot(in);
            if (first < 0 && mm != 0ull) first = b0 + __ffsll((unsigned long long)mm) - 1;
            const int pos = cnt + (int)__popcll(mm & ((1ull << t) - 1ull));
            if (in && pos < 64) sg[pos] = b0 + t;
            cnt += (int)__popcll(mm);
            if (cnt >= 64) break;
        }
        if (cnt < 64)
            for (int k = cnt + t; k < 64; k += 64) sg[k] = first;
    }
    __syncthreads();
    for (int i = t; i < 64 * 32; i += 256) {
        const int n = i >> 5, cc = i & 31;
        *(float4*)&Abuf[n * 132 + cc * 4] =
            *(const float4*)&l1p[((size_t)b * 512 + sg[n]) * 128 + cc * 4];
    }
    if (t < 192) {
        const int n = t / 3, c = t % 3;
        const float4 pp = sp4[sg[n]];
        const float pc = (c == 0) ? pp.x : (c == 1) ? pp.y : pp.z;
        Abuf[n * 132 + 128 + c] = pc - l2xyz[(size_t)bs * 3 + c];
    }
    __syncthreads();
    const int lane = t & 63, wv = t >> 6;
    const int m = lane & 15, q = lane >> 4;
    const int rowA = wv * 16 + m;

    // layer 0: feats (K=128) MFMA + coords/bias epilogue
    f32x4 acc0[8];
    #pragma unroll
    for (int ot = 0; ot < 8; ++ot)
        #pragma unroll
        for (int r = 0; r < 4; ++r) acc0[ot][r] = 0.0f;
    #pragma unroll
    for (int ks = 0; ks < 4; ++ks) {
        float xv[8];
        *(float4*)&xv[0] = *(const float4*)&Abuf[rowA * 132 + ks * 32 + q * 8];
        *(float4*)&xv[4] = *(const float4*)&Abuf[rowA * 132 + ks * 32 + q * 8 + 4];
        SV8 ah;
        #pragma unroll
        for (int j = 0; j < 8; ++j) ah.u[j] = f2bf(xv[j]);
        #pragma unroll
        for (int ot = 0; ot < 8; ++ot) {
            SV8 bh;
            bh.v = *(const short8*)(W0h + (size_t)((ks * 8 + ot) * 64 + lane) * 8);
            acc0[ot] = __builtin_amdgcn_mfma_f32_16x16x32_bf16(ah.v, bh.v, acc0[ot], 0, 0, 0);
        }
    }
    float crd[4][3];
    #pragma unroll
    for (int r = 0; r < 4; ++r) {
        const int n = wv * 16 + q * 4 + r;
        crd[r][0] = Abuf[n * 132 + 128];
        crd[r][1] = Abuf[n * 132 + 129];
        crd[r][2] = Abuf[n * 132 + 130];
    }
    #pragma unroll
    for (int ot = 0; ot < 8; ++ot) {
        const float4 wc = Wc0[ot * 16 + m];
        #pragma unroll
        for (int r = 0; r < 4; ++r) {
            const float v = acc0[ot][r] + wc.w + wc.x * crd[r][0] + wc.y * crd[r][1] + wc.z * crd[r][2];
            Bbuf[(wv * 16 + q * 4 + r) * 132 + ot * 16 + m] = fmaxf(v, 0.0f);
        }
    }
    __syncthreads();

    // layer 1: 128 -> 128
    f32x4 acc1[8];
    #pragma unroll
    for (int ot = 0; ot < 8; ++ot)
        #pragma unroll
        for (int r = 0; r < 4; ++r) acc1[ot][r] = 0.0f;
    #pragma unroll
    for (int ks = 0; ks < 4; ++ks) {
        float xv[8];
        *(float4*)&xv[0] = *(const float4*)&Bbuf[rowA * 132 + ks * 32 + q * 8];
        *(float4*)&xv[4] = *(const float4*)&Bbuf[rowA * 132 + ks * 32 + q * 8 + 4];
        SV8 ah;
        #pragma unroll
        for (int j = 0; j < 8; ++j) ah.u[j] = f2bf(xv[j]);
        #pragma unroll
        for (int ot = 0; ot < 8; ++ot) {
            SV8 bh;
            bh.v = *(const short8*)(W1h + (size_t)((ks * 8 + ot) * 64 + lane) * 8);
            acc1[ot] = __builtin_amdgcn_mfma_f32_16x16x32_bf16(ah.v, bh.v, acc1[ot], 0, 0, 0);
        }
    }
    __syncthreads();
    #pragma unroll
    for (int ot = 0; ot < 8; ++ot) {
        const float bb = b1[ot * 16 + m];
        #pragma unroll
        for (int r = 0; r < 4; ++r)
            Abuf[(wv * 16 + q * 4 + r) * 132 + ot * 16 + m] = fmaxf(acc1[ot][r] + bb, 0.0f);
    }
    __syncthreads();

    // layer 2: 128 -> 256, relu+max
    f32x4 acc2[16];
    #pragma unroll
    for (int ot = 0; ot < 16; ++ot)
        #pragma unroll
        for (int r = 0; r < 4; ++r) acc2[ot][r] = 0.0f;
    #pragma unroll
    for (int ks = 0; ks < 4; ++ks) {
        float xv[8];
        *(float4*)&xv[0] = *(const float4*)&Abuf[rowA * 132 + ks * 32 + q * 8];
        *(float4*)&xv[4] = *(const float4*)&Abuf[rowA * 132 + ks * 32 + q * 8 + 4];
        SV8 ah;
        #pragma unroll
        for (int j = 0; j < 8; ++j) ah.u[j] = f2bf(xv[j]);
        #pragma unroll
        for (int ot = 0; ot < 16; ++ot) {
            SV8 bh;
            bh.v = *(const short8*)(W2h + (size_t)((ks * 16 + ot) * 64 + lane) * 8);
            acc2[ot] = __builtin_amdgcn_mfma_f32_16x16x32_bf16(ah.v, bh.v, acc2[ot], 0, 0, 0);
        }
    }
    __syncthreads();
    #pragma unroll
    for (int ot = 0; ot < 16; ++ot) {
        const float bb = b2[ot * 16 + m];
        float mx = 0.0f;
        #pragma unroll
        for (int r = 0; r < 4; ++r) mx = fmaxf(mx, acc2[ot][r] + bb);
        Bbuf[(wv * 4 + q) * 256 + ot * 16 + m] = mx;
    }
    __syncthreads();
    {
        float v = Bbuf[t];
        #pragma unroll
        for (int rr = 1; rr < 16; ++rr) v = fmaxf(v, Bbuf[rr * 256 + t]);
        X3[(size_t)bs * 288 + 3 + t] = v;
    }
}

// ===================== stage-3 GEMM via MFMA bf16 (no LDS A) ===============
template<int KSTEPS, int OTILES, bool MAXOUT>
__global__ __launch_bounds__(256)
void gemm_mfma_kernel(const float* __restrict__ A, int AS,
                      const ushort* __restrict__ Wh,
                      const float* __restrict__ bias, float* __restrict__ C, int O) {
    __shared__ float part[16][OTILES * 16];
    const int t = threadIdx.x, lane = t & 63, wv = t >> 6;
    const int m = lane & 15, q = lane >> 4;
    const int rowA = blockIdx.x * 64 + wv * 16 + m;
    const int bo = blockIdx.y, OT = O >> 4;
    f32x4 acc[OTILES];
    #pragma unroll
    for (int ot = 0; ot < OTILES; ++ot)
        #pragma unroll
        for (int r = 0; r < 4; ++r) acc[ot][r] = 0.0f;
    for (int ks = 0; ks < KSTEPS; ++ks) {
        float xv[8];
        *(float4*)&xv[0] = *(const float4*)&A[(size_t)rowA * AS + ks * 32 + q * 8];
        *(float4*)&xv[4] = *(const float4*)&A[(size_t)rowA * AS + ks * 32 + q * 8 + 4];
        SV8 ah;
        #pragma unroll
        for (int j = 0; j < 8; ++j) ah.u[j] = f2bf(xv[j]);
        #pragma unroll
        for (int ot = 0; ot < OTILES; ++ot) {
            const size_t wb = (size_t)((ks * OT + bo * OTILES + ot) * 64 + lane) * 8;
            SV8 bh;
            bh.v = *(const short8*)(Wh + wb);
            acc[ot] = __builtin_amdgcn_mfma_f32_16x16x32_bf16(ah.v, bh.v, acc[ot], 0, 0, 0);
        }
    }
    if (!MAXOUT) {
        #pragma unroll
        for (int ot = 0; ot < OTILES; ++ot) {
            const int col = (bo * OTILES + ot) * 16 + m;
            const float bb = bias[col];
            #pragma unroll
            for (int r = 0; r < 4; ++r) {
                const int row = blockIdx.x * 64 + wv * 16 + q * 4 + r;
                C[(size_t)row * O + col] = fmaxf(acc[ot][r] + bb, 0.0f);
            }
        }
    } else {
        #pragma unroll
        for (int ot = 0; ot < OTILES; ++ot) {
            const int col = (bo * OTILES + ot) * 16 + m;
            const float bb = bias[col];
            float mx = 0.0f;
            #pragma unroll
            for (int r = 0; r < 4; ++r) mx = fmaxf(mx, acc[ot][r] + bb);
            part[wv * 4 + q][ot * 16 + m] = mx;
        }
        __syncthreads();
        for (int o = t; o < OTILES * 16; o += 256) {
            float v = part[0][o];
            #pragma unroll
            for (int rr = 1; rr < 16; ++rr) v = fmaxf(v, part[rr][o]);
            C[(size_t)blockIdx.x * O + bo * OTILES * 16 + o] = v;
        }
    }
}

// ================= fused FC head (P3 row-max + 3 layers, fp32) =============
__global__ __launch_bounds__(256)
void fchead_kernel(const float* __restrict__ P3,
                   const float* __restrict__ f1w, const float* __restrict__ f1b,
                   const float* __restrict__ f2w, const float* __restrict__ f2b,
                   const float* __restrict__ f3w, const float* __restrict__ f3b,
                   float* __restrict__ out) {
    __shared__ __align__(16) float x[1024];
    __shared__ __align__(16) float h1[512];
    __shared__ __align__(16) float h2[256];
    const int t = threadIdx.x, b = blockIdx.x;
    for (int i = t; i < 1024; i += 256)
        x[i] = fmaxf(P3[(size_t)(2*b)*1024 + i], P3[(size_t)(2*b+1)*1024 + i]);
    __syncthreads();
    #pragma unroll
    for (int oo = 0; oo < 2; ++oo) {       // f1: 1024 -> 512
        const int o = t + oo * 256;
        const float4* wr = (const float4*)(f1w + (size_t)o * 1024);
        float s0 = 0, s1 = 0, s2 = 0, s3 = 0;
        for (int c = 0; c < 256; ++c) {
            const float4 w4 = wr[c];
            const float4 xv = *(const float4*)&x[c * 4];
            s0 += w4.x * xv.x; s1 += w4.y * xv.y; s2 += w4.z * xv.z; s3 += w4.w * xv.w;
        }
        h1[o] = fmaxf(f1b[o] + ((s0 + s1) + (s2 + s3)), 0.0f);
    }
    __syncthreads();
    {                                       // f2: 512 -> 256
        const float4* wr = (const float4*)(f2w + (size_t)t * 512);
        float s0 = 0, s1 = 0, s2 = 0, s3 = 0;
        for (int c = 0; c < 128; ++c) {
            const float4 w4 = wr[c];
            const float4 xv = *(const float4*)&h1[c * 4];
            s0 += w4.x * xv.x; s1 += w4.y * xv.y; s2 += w4.z * xv.z; s3 += w4.w * xv.w;
        }
        h2[t] = fmaxf(f2b[t] + ((s0 + s1) + (s2 + s3)), 0.0f);
    }
    __syncthreads();
    if (t < 6) {                            // f3: 256 -> 6
        const float4* wr = (const float4*)(f3w + (size_t)t * 256);
        float s0 = 0, s1 = 0, s2 = 0, s3 = 0;
        for (int c = 0; c < 64; ++c) {
            const float4 w4 = wr[c];
            const float4 xv = *(const float4*)&h2[c * 4];
            s0 += w4.x * xv.x; s1 += w4.y * xv.y; s2 += w4.z * xv.z; s3 += w4.w * xv.w;
        }
        out[b * 6 + t] = f3b[t] + ((s0 + s1) + (s2 + s3));
    }
}

// ============================ launch =======================================
extern "C" void kernel_launch(void* const* d_in, const int* in_sizes, int n_in,
                              void* d_out, int out_size, void* d_ws, size_t ws_size,
                              hipStream_t stream) {
    const float* xyz  = (const float*)d_in[0];
    const float* s1w0 = (const float*)d_in[1];  const float* s1b0 = (const float*)d_in[2];
    const float* s1w1 = (const float*)d_in[3];  const float* s1b1 = (const float*)d_in[4];
    const float* s1w2 = (const float*)d_in[5];  const float* s1b2 = (const float*)d_in[6];
    const float* s2w0 = (const float*)d_in[7];  const float* s2b0 = (const float*)d_in[8];
    const float* s2w1 = (const float*)d_in[9];  const float* s2b1 = (const float*)d_in[10];
    const float* s2w2 = (const float*)d_in[11]; const float* s2b2 = (const float*)d_in[12];
    const float* s3w0 = (const float*)d_in[13]; const float* s3b0 = (const float*)d_in[14];
    const float* s3w1 = (const float*)d_in[15]; const float* s3b1 = (const float*)d_in[16];
    const float* s3w2 = (const float*)d_in[17]; const float* s3b2 = (const float*)d_in[18];
    const float* f1w  = (const float*)d_in[19]; const float* f1b  = (const float*)d_in[20];
    const float* f2w  = (const float*)d_in[21]; const float* f2b  = (const float*)d_in[22];
    const float* f3w  = (const float*)d_in[23]; const float* f3b  = (const float*)d_in[24];

    char* ws = (char*)d_ws;
    float* l1_xyz = (float*)(ws + 0);              // 32*512*3
    int*   gidx1  = (int*)  (ws + 196608);         // 32*512*32
    float* l1p    = (float*)(ws + 2293760);        // 32*512*128
    float* l2_xyz = (float*)(ws + 10682368);       // 32*128*3
    float* X3p    = (float*)(ws + 11780096);       // 4096*288 (zero-padded)
    const size_t PK = 16498688;                    // pack region (h-only)
    float4* Wc1   = (float4*)(ws + PK + 0);
    ushort* M1W1h = (ushort*)(ws + PK + 1024);
    ushort* M1W2h = (ushort*)(ws + PK + 17408);
    ushort* W0h   = (ushort*)(ws + PK + 50176);
    ushort* W1h   = (ushort*)(ws + PK + 115712);
    ushort* W2h   = (ushort*)(ws + PK + 181248);
    float4* Wc0   = (float4*)(ws + PK + 312320);
    ushort* S3W0h = (ushort*)(ws + PK + 314368);
    ushort* S3W1h = (ushort*)(ws + PK + 609280);
    ushort* S3W2h = (ushort*)(ws + PK + 1133568);
    float* Y1   = (float*)(ws + 19729408);         // 4096*256
    float* Y2   = (float*)(ws + 23923712);         // 4096*512
    float* P3   = (float*)(ws + 32312320);         // 64*1024 fp32 partial maxima

    // Stage 1 (fps1 on blocks 0..31, weight pack on blocks 32..)
    fps1_prep_kernel<<<3186, 256, 0, stream>>>(xyz, l1_xyz,
        s1w0, s1b0, Wc1, s1w1, M1W1h, s1w2, M1W2h,
        s3w0, S3W0h, s3w1, S3W1h, s3w2, S3W2h,
        s2w0, s2b0, Wc0, W0h, s2w1, W1h, s2w2, W2h);
    bq_kernel<4096, 32, true, 1024><<<1024, 1024, 0, stream>>>(
        (float)(0.2 * 0.2), xyz, l1_xyz, gidx1, 512);
    {
        dim3 g(32, 257);   // x=batch, y=role; y==0 -> fps2 (linear 0..31)
        mlp1_kernel<<<g, 256, 0, stream>>>(xyz, l1_xyz, l2_xyz, gidx1,
            Wc1, M1W1h, s1b1, M1W2h, s1b2, l1p);
    }

    // Stage 2 (ball query inlined into mlp2)
    mlp2_kernel<<<4096, 256, 0, stream>>>(l1_xyz, l1p, l2_xyz,
        W0h, Wc0, W1h, s2b1, W2h, s2b2, X3p);

    // Stage 3 (bf16 MFMA GEMMs; OTILES=4 everywhere = R13 schedule)
    {
        dim3 g1(64, 4);
        gemm_mfma_kernel<9,  4, false><<<g1, 256, 0, stream>>>(X3p, 288, S3W0h, s3b0, Y1, 256);
        dim3 g2(64, 8);
        gemm_mfma_kernel<8,  4, false><<<g2, 256, 0, stream>>>(Y1, 256, S3W1h, s3b1, Y2, 512);
        dim3 g3(64, 16);
        gemm_mfma_kernel<16, 4, true ><<<g3, 256, 0, stream>>>(Y2, 512, S3W2h, s3b2, P3, 1024);
    }

    // Fused FC head (row-max of P3 + 1024->512->256->6)
    fchead_kernel<<<32, 256, 0, stream>>>(P3, f1w, f1b, f2w, f2b, f3w, f3b, (float*)d_out);
    (void)in_sizes; (void)n_in; (void)out_size; (void)ws_size;
}